// Round 1
// baseline (1393.917 us; speedup 1.0000x reference)
//
#include <hip/hip_runtime.h>

#define NN 32768
#define HWID 448
// H cols: 0:80 h | 80:160 hG1 | 160:240 hG2 | 240:249 f1 | 249:258 g1 | 258:267 f2 | 267:276 g2 |
//         276:280 pad | 280:360 hvo1 | 360:440 hvo2 | 440:448 pad

// ---- workspace float offsets ----
#define OFF_G     0
#define OFF_M     25600
#define OFF_FF    51200
#define OFF_FG    54080
#define OFF_CC    56960
#define OFF_C2    57284
#define OFF_CW    60164
#define OFF_STATS 133636
#define OFF_MS    133956
#define OFF_H     134148
#define OFF_U     14814212

__global__ __launch_bounds__(256) void k_prep_small(const float* __restrict__ qkvw,
                                                    const float* __restrict__ qkvb,
                                                    const float* __restrict__ outw,
                                                    float* __restrict__ ws) {
    int combo = blockIdx.y;
    int e = blockIdx.x * 256 + threadIdx.x;
    const float* Wq = qkvw + combo * 267 * 89;
    const float* Wk = Wq + 89 * 89;
    const float* Wv = Wq + 178 * 89;
    const float* bq = qkvb + combo * 267;
    const float* bk = bq + 89;
    const float* bv = bq + 178;
    const float* Wo = outw + combo * 89 * 89;
    if (e < 6400) {
        int a = e / 80, b = e % 80;
        float s = 0.f;
        for (int j = 0; j < 89; ++j) s += Wq[j*89+a] * Wk[j*89+b];
        ws[OFF_G + combo*6400 + e] = s;
    } else if (e < 12800) {
        int e2 = e - 6400; int f = e2 / 80, c = e2 % 80;
        float s = 0.f;
        for (int j = 0; j < 89; ++j) s += Wo[f*89+j] * Wv[j*89+c];
        ws[OFF_M + combo*6400 + e2] = s;
    } else if (e < 13520) {
        int e3 = e - 12800; int a = e3 / 9, t = e3 % 9;
        float s = 0.f;
        for (int j = 0; j < 89; ++j) s += Wq[j*89+a] * (Wk[j*89+80+t] + bk[j]);
        ws[OFF_FF + combo*720 + e3] = s;
    } else if (e < 14240) {
        int e4 = e - 13520; int a = e4 / 9, si = e4 % 9;
        float s = 0.f;
        for (int j = 0; j < 89; ++j) s += Wk[j*89+a] * (Wq[j*89+80+si] + bq[j]);
        ws[OFF_FG + combo*720 + e4] = s;
    } else if (e < 14321) {
        int e5 = e - 14240; int si = e5 / 9, t = e5 % 9;
        float s = 0.f;
        for (int j = 0; j < 89; ++j) s += (Wq[j*89+80+si] + bq[j]) * (Wk[j*89+80+t] + bk[j]);
        ws[OFF_CC + combo*81 + e5] = s;
    } else if (e < 15041) {
        int e6 = e - 14321; int t = e6 / 80, f = e6 % 80;
        float s = 0.f;
        for (int j = 0; j < 89; ++j) s += Wo[f*89+j] * (Wv[j*89+80+t] + bv[j]);
        ws[OFF_C2 + combo*720 + e6] = s;
    }
}

__global__ __launch_bounds__(256) void k_prep_cw(const float* __restrict__ W1,
                                                 const float* __restrict__ W2,
                                                 float* __restrict__ ws) {
    int l = blockIdx.y;
    int e = blockIdx.x * 256 + threadIdx.x;
    if (e >= 82 * 448) return;
    int k = e / 448, j = e % 448;
    int K = (l == 0) ? 82 : 80;
    float val = 0.f;
    if (k < K) {
        const float* Wr = ((l == 0) ? W1 : W2) + k * 80;
        if (j < 80) {
            val = Wr[j];
        } else if (j < 240) {
            int m = (j - 80) / 80, col = (j - 80) % 80;
            const float* G = ws + OFF_G + (l*2+m)*6400;
            float s = 0.f;
            for (int c = 0; c < 80; ++c) s += Wr[c] * G[c*80 + col];
            val = s;
        } else if (j < 276) {
            int q = j - 240; int m = q / 18; int qq = q % 18;
            int combo = l*2 + m;
            if (qq < 9) {
                const float* Ff = ws + OFF_FF + combo*720;
                float s = 0.f;
                for (int c = 0; c < 80; ++c) s += Wr[c] * Ff[c*9 + qq];
                val = s;
            } else {
                const float* Fg = ws + OFF_FG + combo*720;
                float s = 0.f;
                for (int c = 0; c < 80; ++c) s += Wr[c] * Fg[c*9 + qq - 9];
                val = s;
            }
        } else if (j >= 280 && j < 440) {
            int m = (j - 280) / 80, f = (j - 280) % 80;
            const float* M = ws + OFF_M + (l*2+m)*6400 + f*80;
            float s = 0.f;
            for (int c = 0; c < 80; ++c) s += Wr[c] * M[c];
            val = s;
        }
    }
    ws[OFF_CW + (size_t)l*82*448 + e] = val;
}

template<int K, bool TRANS>
__global__ __launch_bounds__(256) void k_gemm(const float* __restrict__ A,
                                              const float* __restrict__ CW,
                                              float* __restrict__ H,
                                              const float* __restrict__ ms) {
    __shared__ __align__(16) float AsT[K][72];
    __shared__ __align__(16) float Bs[K][68];
    int tid = threadIdx.x;
    int n0 = blockIdx.x * 64;
    int j0 = blockIdx.y * 64;
    float scale0 = 0.f;
    if constexpr (TRANS) scale0 = ms[80];
    for (int idx = tid; idx < 64 * K; idx += 256) {
        int r = idx / K, k = idx - r * K;
        float v = A[(size_t)(n0 + r) * K + k];
        if constexpr (TRANS) v = fmaxf(0.f, (v - ms[k]) * scale0);
        AsT[k][r] = v;
    }
    for (int idx = tid; idx < K * 64; idx += 256) {
        int k = idx >> 6, c = idx & 63;
        Bs[k][c] = CW[k * 448 + j0 + c];
    }
    __syncthreads();
    int r0 = (tid >> 4) * 4, c0 = (tid & 15) * 4;
    float acc[4][4] = {};
    for (int k = 0; k < K; ++k) {
        float4 a4 = *(const float4*)(&AsT[k][r0]);
        float4 b4 = *(const float4*)(&Bs[k][c0]);
        acc[0][0] += a4.x*b4.x; acc[0][1] += a4.x*b4.y; acc[0][2] += a4.x*b4.z; acc[0][3] += a4.x*b4.w;
        acc[1][0] += a4.y*b4.x; acc[1][1] += a4.y*b4.y; acc[1][2] += a4.y*b4.z; acc[1][3] += a4.y*b4.w;
        acc[2][0] += a4.z*b4.x; acc[2][1] += a4.z*b4.y; acc[2][2] += a4.z*b4.z; acc[2][3] += a4.z*b4.w;
        acc[3][0] += a4.w*b4.x; acc[3][1] += a4.w*b4.y; acc[3][2] += a4.w*b4.z; acc[3][3] += a4.w*b4.w;
    }
    for (int i = 0; i < 4; ++i) {
        float4 v = make_float4(acc[i][0], acc[i][1], acc[i][2], acc[i][3]);
        *(float4*)(&H[(size_t)(n0 + r0 + i) * HWID + j0 + c0]) = v;
    }
}

// ---------------- fused attention v4: 4 nodes/wave software pipeline, zero HW barriers ----------
// All LDS is wave-private (sS[wave], sP[wave]); cross-lane LDS comm relies on same-wave DS
// in-order completion + compiler-only wave_barrier fences. sCC removed from LDS (4 reg loads).
// While node i computes from LDS, node i+1's 9-row gather (9 float4/lane) + f/g scalars are
// in flight in registers (issue-early / write-late) -> per-wave outstanding loads stay high.
// NOTE: still no min-waves arg in __launch_bounds__ (R5 spill lesson).

__device__ __forceinline__ void wsync() {
    asm volatile("" ::: "memory");
    __builtin_amdgcn_wave_barrier();
    asm volatile("" ::: "memory");
}

#define ISSUE_STAGE(st, nv)                                                 \
    _Pragma("unroll")                                                       \
    for (int j = 0; j < 9; ++j) {                                           \
        int i = lane + 64 * j;                                              \
        if (i < 540) {                                                      \
            int row = i / 60, c4 = i - row * 60;                            \
            int r = __shfl(nv, row);                                        \
            st[j] = *(const float4*)(Hbuf + (size_t)r * HWID + c4 * 4);     \
        }                                                                   \
    }

#define ISSUE_FG(fg, nv) {                                                  \
    int rs1 = __shfl(nv, s1), rt1 = __shfl(nv, t1);                         \
    int rs2 = __shfl(nv, s2), rt2 = __shfl(nv, t2);                         \
    const float* pS1 = Hbuf + (size_t)rs1 * HWID;                           \
    const float* pT1 = Hbuf + (size_t)rt1 * HWID;                           \
    const float* pS2 = Hbuf + (size_t)rs2 * HWID;                           \
    const float* pT2 = Hbuf + (size_t)rt2 * HWID;                           \
    fg[0] = pS1[240 + t1]; fg[1] = pT1[249 + s1];                           \
    fg[2] = pS1[258 + t1]; fg[3] = pT1[267 + s1];                           \
    fg[4] = pS2[240 + t2]; fg[5] = pT2[249 + s2];                           \
    fg[6] = pS2[258 + t2]; fg[7] = pT2[267 + s2]; }

#define WRITE_STAGE(st)                                                     \
    _Pragma("unroll")                                                       \
    for (int j = 0; j < 9; ++j) {                                           \
        int i = lane + 64 * j;                                              \
        if (i < 540) {                                                      \
            int row = i / 60, c4 = i - row * 60;                            \
            *(float4*)(&sSw[row][c4 * 4]) = st[j];                          \
        }                                                                   \
    }

__global__ __launch_bounds__(128) void k_attn(const float* __restrict__ ws,
                                              const float* __restrict__ Hbuf,
                                              const int* __restrict__ nbr,
                                              const float* __restrict__ outb,
                                              const float* __restrict__ bvec,
                                              float* __restrict__ u,
                                              int l) {
    __shared__ __align__(16) float sS[2][9][242];  // wave-private: h | hG1 | hG2
    __shared__ float sP[2][2][9][9];               // wave-private scores
    int tid = threadIdx.x;
    int wave = tid >> 6, lane = tid & 63;
    float (*sSw)[242] = sS[wave];
    float (*sPw)[9][9] = sP[wave];
    int nbase = (blockIdx.x * 2 + wave) * 4;

    int pp2 = (lane < 17) ? (lane + 64) : 80;
    int s1 = lane / 9, t1 = lane - s1 * 9;
    int s2 = pp2 / 9, t2 = pp2 - s2 * 9;

    // node-invariant scalars: cc terms + bias
    const float* ccp = ws + OFF_CC + (l * 2) * 81;
    float cc0a = ccp[lane],  cc1a = ccp[81 + lane];
    float cc0b = ccp[pp2],   cc1b = ccp[81 + pp2];
    int fA = (lane < 80) ? lane : 0;
    float biasA = outb[(l*2)*89 + fA] + outb[(l*2+1)*89 + fA] + bvec[fA];
    int fB = lane + 64;
    float biasB = (fB < 80) ? (outb[(l*2)*89 + fB] + outb[(l*2+1)*89 + fB] + bvec[fB]) : 0.f;

    // all 4 neighbor vectors up front
    int li = (lane < 9) ? lane : 8;
    int nvA = nbr[(nbase + 0) * 9 + li];
    int nvB = nbr[(nbase + 1) * 9 + li];
    int nvC = nbr[(nbase + 2) * 9 + li];
    int nvD = nbr[(nbase + 3) * 9 + li];

    const float rsE = 1.0f / 9.433981132056603f;  // 1/sqrt(89)

    float4 st[9];
    float fgc[8], fgn[8];
    ISSUE_STAGE(st, nvA);
    ISSUE_FG(fgc, nvA);

    for (int it = 0; it < 4; ++it) {
        int n = nbase + it;
        int nv = nvA;

        WRITE_STAGE(st);           // compiler waits vmcnt on st; ds_write wave-private LDS
        wsync();

        // issue next node's gather while this node computes (ds_write captured st at issue;
        // a wave's DS ops complete in order, so reload of st regs is safe)
        if (it < 3) {
            ISSUE_STAGE(st, nvB);
            ISSUE_FG(fgn, nvB);
        }

        // ---- phase A: scores, pair 1 (all 64 lanes) ----
        {
            float a0 = 0.f, a1 = 0.f, b0 = 0.f, b1 = 0.f;
            #pragma unroll
            for (int i = 0; i < 20; ++i) {
                float4 hh = *(const float4*)(&sSw[t1][4*i]);
                float4 g1 = *(const float4*)(&sSw[s1][80 + 4*i]);
                float4 g2 = *(const float4*)(&sSw[s1][160 + 4*i]);
                a0 += g1.x*hh.x + g1.y*hh.y; a1 += g1.z*hh.z + g1.w*hh.w;
                b0 += g2.x*hh.x + g2.y*hh.y; b1 += g2.z*hh.z + g2.w*hh.w;
            }
            sPw[0][s1][t1] = (a0 + a1 + fgc[0] + fgc[1] + cc0a) * rsE;
            sPw[1][s1][t1] = (b0 + b1 + fgc[2] + fgc[3] + cc1a) * rsE;
        }
        // ---- phase A: pair 2 (17 lanes) ----
        if (lane < 17) {
            float a0 = 0.f, a1 = 0.f, b0 = 0.f, b1 = 0.f;
            #pragma unroll
            for (int i = 0; i < 20; ++i) {
                float4 hh = *(const float4*)(&sSw[t2][4*i]);
                float4 g1 = *(const float4*)(&sSw[s2][80 + 4*i]);
                float4 g2 = *(const float4*)(&sSw[s2][160 + 4*i]);
                a0 += g1.x*hh.x + g1.y*hh.y; a1 += g1.z*hh.z + g1.w*hh.w;
                b0 += g2.x*hh.x + g2.y*hh.y; b1 += g2.z*hh.z + g2.w*hh.w;
            }
            sPw[0][s2][t2] = (a0 + a1 + fgc[4] + fgc[5] + cc0b) * rsE;
            sPw[1][s2][t2] = (b0 + b1 + fgc[6] + fgc[7] + cc1b) * rsE;
        }
        wsync();

        // ---- phase B: softmax over t (18 rows) ----
        if (lane < 18) {
            int m = lane / 9, s = lane - m*9;
            float row[9]; float mx = -1e30f;
            #pragma unroll
            for (int t = 0; t < 9; ++t) { row[t] = sPw[m][s][t]; mx = fmaxf(mx, row[t]); }
            float sm = 0.f;
            #pragma unroll
            for (int t = 0; t < 9; ++t) { row[t] = __expf(row[t] - mx); sm += row[t]; }
            float inv = 1.f / sm;
            #pragma unroll
            for (int t = 0; t < 9; ++t) sPw[m][s][t] = row[t] * inv;
        }
        wsync();

        // ---- phase C: PV + base + max + bias ----
        {
            int rr[9];
            #pragma unroll
            for (int s = 0; s < 9; ++s) rr[s] = __shfl(nv, s);
            for (int f = lane; f < 80; f += 64) {
                float acc[9] = {};
                #pragma unroll
                for (int m = 0; m < 2; ++m) {
                    const float* c2 = ws + OFF_C2 + (l*2+m)*720;
                    #pragma unroll
                    for (int t = 0; t < 9; ++t) {
                        float vv = Hbuf[(size_t)rr[t]*HWID + 280 + m*80 + f] + c2[t*80 + f];
                        #pragma unroll
                        for (int s = 0; s < 9; ++s) acc[s] += sPw[m][s][t] * vv;
                    }
                }
                float mx = -1e30f;
                #pragma unroll
                for (int s = 0; s < 9; ++s) mx = fmaxf(mx, acc[s] + sSw[s][f]);
                u[(size_t)n*80 + f] = mx + ((f == lane) ? biasA : biasB);
            }
        }
        wsync();   // all reads of sSw done before next WRITE_STAGE

        // rotate pipeline state
        nvA = nvB; nvB = nvC; nvC = nvD;
        #pragma unroll
        for (int q = 0; q < 8; ++q) fgc[q] = fgn[q];
    }
}

__global__ __launch_bounds__(256) void k_colreduce(const float* __restrict__ u, float* __restrict__ stats) {
    __shared__ float ps[3][80], ps2[3][80];
    int tid = threadIdx.x;
    int c = tid % 80, rg = tid / 80;
    if (rg < 3) {
        float s = 0.f, s2 = 0.f;
        int rbase = blockIdx.x * 48 + rg * 16;
        for (int i = 0; i < 16; ++i) {
            int rw = rbase + i;
            if (rw < NN) {
                float v = u[(size_t)rw*80 + c];
                s += v; s2 += v*v;
            }
        }
        ps[rg][c] = s; ps2[rg][c] = s2;
    }
    __syncthreads();
    if (tid < 80) {
        atomicAdd(&stats[tid],      ps[0][tid] + ps[1][tid] + ps[2][tid]);
        atomicAdd(&stats[80 + tid], ps2[0][tid] + ps2[1][tid] + ps2[2][tid]);
    }
}

__global__ __launch_bounds__(128) void k_normscale(const float* __restrict__ stats, float* __restrict__ ms) {
    __shared__ float red[80];
    int t = threadIdx.x;
    if (t < 80) {
        float mean = stats[t] * (1.0f / (float)NN);
        ms[t] = mean;
        red[t] = stats[80 + t] - (float)NN * mean * mean;
    }
    __syncthreads();
    if (t == 0) {
        float ss = 0.f;
        for (int i = 0; i < 80; ++i) ss += red[i];
        ms[80] = 1.0f / sqrtf(1e-5f + ss * (1.0f / (float)NN));
    }
}

__global__ __launch_bounds__(256) void k_final(const float* __restrict__ x,
                                               const float* __restrict__ u2,
                                               const float* __restrict__ ms,
                                               float* __restrict__ out) {
    int g = blockIdx.x * 256 + threadIdx.x;
    int n = g / 80, f = g % 80;
    float scale0 = ms[80];
    float v = fmaxf(0.f, (u2[g] - ms[f]) * scale0);
    float o = x[(size_t)n*82 + f] + v;
    if (f == 79 && (o > 1.0f || o < -1.0f)) o = 0.f;
    out[g] = o * 0.5f;
}

extern "C" void kernel_launch(void* const* d_in, const int* in_sizes, int n_in,
                              void* d_out, int out_size, void* d_ws, size_t ws_size,
                              hipStream_t stream) {
    const float* x    = (const float*)d_in[0];
    const float* W1   = (const float*)d_in[1];
    const float* b1   = (const float*)d_in[2];
    const float* W2   = (const float*)d_in[3];
    const float* b2   = (const float*)d_in[4];
    const float* qkvw = (const float*)d_in[5];
    const float* qkvb = (const float*)d_in[6];
    const float* outw = (const float*)d_in[7];
    const float* outb = (const float*)d_in[8];
    const int*   nbr  = (const int*)d_in[9];
    float* ws = (float*)d_ws;
    float* out = (float*)d_out;

    float* H = ws + OFF_H;
    float* u = ws + OFF_U;

    hipMemsetAsync(ws + OFF_STATS, 0, 320 * sizeof(float), stream);
    k_prep_small<<<dim3(59, 4), 256, 0, stream>>>(qkvw, qkvb, outw, ws);
    k_prep_cw<<<dim3(144, 2), 256, 0, stream>>>(W1, W2, ws);

    k_gemm<82, false><<<dim3(512, 7), 256, 0, stream>>>(x, ws + OFF_CW, H, nullptr);
    k_attn<<<4096, 128, 0, stream>>>(ws, H, nbr, outb, b1, u, 0);
    k_colreduce<<<683, 256, 0, stream>>>(u, ws + OFF_STATS);
    k_normscale<<<1, 128, 0, stream>>>(ws + OFF_STATS, ws + OFF_MS);

    k_gemm<80, true><<<dim3(512, 7), 256, 0, stream>>>(u, ws + OFF_CW + 82*448, H, ws + OFF_MS);
    k_attn<<<4096, 128, 0, stream>>>(ws, H, nbr, outb, b2, u, 1);
    k_colreduce<<<683, 256, 0, stream>>>(u, ws + OFF_STATS + 160);
    k_normscale<<<1, 128, 0, stream>>>(ws + OFF_STATS + 160, ws + OFF_MS + 96);

    k_final<<<10240, 256, 0, stream>>>(x, u, ws + OFF_MS + 96, out);
}

// Round 2
// 973.095 us; speedup vs baseline: 1.4325x; 1.4325x over previous
//
#include <hip/hip_runtime.h>

#define NN 32768
#define HWID 448
// H cols: 0:80 h | 80:160 hG1 | 160:240 hG2 | 240:249 f1 | 249:258 g1 | 258:267 f2 | 267:276 g2 |
//         276:280 pad | 280:360 hvo1 | 360:440 hvo2 | 440:448 pad

// ---- workspace float offsets ----
#define OFF_G     0
#define OFF_M     25600
#define OFF_FF    51200
#define OFF_FG    54080
#define OFF_CC    56960
#define OFF_C2    57284
#define OFF_CW    60164
#define OFF_STATS 133636
#define OFF_MS    133956
#define OFF_H     134148
#define OFF_U     14814212

__global__ __launch_bounds__(256) void k_prep_small(const float* __restrict__ qkvw,
                                                    const float* __restrict__ qkvb,
                                                    const float* __restrict__ outw,
                                                    float* __restrict__ ws) {
    int combo = blockIdx.y;
    int e = blockIdx.x * 256 + threadIdx.x;
    const float* Wq = qkvw + combo * 267 * 89;
    const float* Wk = Wq + 89 * 89;
    const float* Wv = Wq + 178 * 89;
    const float* bq = qkvb + combo * 267;
    const float* bk = bq + 89;
    const float* bv = bq + 178;
    const float* Wo = outw + combo * 89 * 89;
    if (e < 6400) {
        int a = e / 80, b = e % 80;
        float s = 0.f;
        for (int j = 0; j < 89; ++j) s += Wq[j*89+a] * Wk[j*89+b];
        ws[OFF_G + combo*6400 + e] = s;
    } else if (e < 12800) {
        int e2 = e - 6400; int f = e2 / 80, c = e2 % 80;
        float s = 0.f;
        for (int j = 0; j < 89; ++j) s += Wo[f*89+j] * Wv[j*89+c];
        ws[OFF_M + combo*6400 + e2] = s;
    } else if (e < 13520) {
        int e3 = e - 12800; int a = e3 / 9, t = e3 % 9;
        float s = 0.f;
        for (int j = 0; j < 89; ++j) s += Wq[j*89+a] * (Wk[j*89+80+t] + bk[j]);
        ws[OFF_FF + combo*720 + e3] = s;
    } else if (e < 14240) {
        int e4 = e - 13520; int a = e4 / 9, si = e4 % 9;
        float s = 0.f;
        for (int j = 0; j < 89; ++j) s += Wk[j*89+a] * (Wq[j*89+80+si] + bq[j]);
        ws[OFF_FG + combo*720 + e4] = s;
    } else if (e < 14321) {
        int e5 = e - 14240; int si = e5 / 9, t = e5 % 9;
        float s = 0.f;
        for (int j = 0; j < 89; ++j) s += (Wq[j*89+80+si] + bq[j]) * (Wk[j*89+80+t] + bk[j]);
        ws[OFF_CC + combo*81 + e5] = s;
    } else if (e < 15041) {
        int e6 = e - 14321; int t = e6 / 80, f = e6 % 80;
        float s = 0.f;
        for (int j = 0; j < 89; ++j) s += Wo[f*89+j] * (Wv[j*89+80+t] + bv[j]);
        ws[OFF_C2 + combo*720 + e6] = s;
    }
}

__global__ __launch_bounds__(256) void k_prep_cw(const float* __restrict__ W1,
                                                 const float* __restrict__ W2,
                                                 float* __restrict__ ws) {
    int l = blockIdx.y;
    int e = blockIdx.x * 256 + threadIdx.x;
    if (e >= 82 * 448) return;
    int k = e / 448, j = e % 448;
    int K = (l == 0) ? 82 : 80;
    float val = 0.f;
    if (k < K) {
        const float* Wr = ((l == 0) ? W1 : W2) + k * 80;
        if (j < 80) {
            val = Wr[j];
        } else if (j < 240) {
            int m = (j - 80) / 80, col = (j - 80) % 80;
            const float* G = ws + OFF_G + (l*2+m)*6400;
            float s = 0.f;
            for (int c = 0; c < 80; ++c) s += Wr[c] * G[c*80 + col];
            val = s;
        } else if (j < 276) {
            int q = j - 240; int m = q / 18; int qq = q % 18;
            int combo = l*2 + m;
            if (qq < 9) {
                const float* Ff = ws + OFF_FF + combo*720;
                float s = 0.f;
                for (int c = 0; c < 80; ++c) s += Wr[c] * Ff[c*9 + qq];
                val = s;
            } else {
                const float* Fg = ws + OFF_FG + combo*720;
                float s = 0.f;
                for (int c = 0; c < 80; ++c) s += Wr[c] * Fg[c*9 + qq - 9];
                val = s;
            }
        } else if (j >= 280 && j < 440) {
            int m = (j - 280) / 80, f = (j - 280) % 80;
            const float* M = ws + OFF_M + (l*2+m)*6400 + f*80;
            float s = 0.f;
            for (int c = 0; c < 80; ++c) s += Wr[c] * M[c];
            val = s;
        }
    }
    ws[OFF_CW + (size_t)l*82*448 + e] = val;
}

template<int K, bool TRANS>
__global__ __launch_bounds__(256) void k_gemm(const float* __restrict__ A,
                                              const float* __restrict__ CW,
                                              float* __restrict__ H,
                                              const float* __restrict__ ms) {
    __shared__ __align__(16) float AsT[K][72];
    __shared__ __align__(16) float Bs[K][68];
    int tid = threadIdx.x;
    int n0 = blockIdx.x * 64;
    int j0 = blockIdx.y * 64;
    float scale0 = 0.f;
    if constexpr (TRANS) scale0 = ms[80];
    for (int idx = tid; idx < 64 * K; idx += 256) {
        int r = idx / K, k = idx - r * K;
        float v = A[(size_t)(n0 + r) * K + k];
        if constexpr (TRANS) v = fmaxf(0.f, (v - ms[k]) * scale0);
        AsT[k][r] = v;
    }
    for (int idx = tid; idx < K * 64; idx += 256) {
        int k = idx >> 6, c = idx & 63;
        Bs[k][c] = CW[k * 448 + j0 + c];
    }
    __syncthreads();
    int r0 = (tid >> 4) * 4, c0 = (tid & 15) * 4;
    float acc[4][4] = {};
    for (int k = 0; k < K; ++k) {
        float4 a4 = *(const float4*)(&AsT[k][r0]);
        float4 b4 = *(const float4*)(&Bs[k][c0]);
        acc[0][0] += a4.x*b4.x; acc[0][1] += a4.x*b4.y; acc[0][2] += a4.x*b4.z; acc[0][3] += a4.x*b4.w;
        acc[1][0] += a4.y*b4.x; acc[1][1] += a4.y*b4.y; acc[1][2] += a4.y*b4.z; acc[1][3] += a4.y*b4.w;
        acc[2][0] += a4.z*b4.x; acc[2][1] += a4.z*b4.y; acc[2][2] += a4.z*b4.z; acc[2][3] += a4.z*b4.w;
        acc[3][0] += a4.w*b4.x; acc[3][1] += a4.w*b4.y; acc[3][2] += a4.w*b4.z; acc[3][3] += a4.w*b4.w;
    }
    for (int i = 0; i < 4; ++i) {
        float4 v = make_float4(acc[i][0], acc[i][1], acc[i][2], acc[i][3]);
        *(float4*)(&H[(size_t)(n0 + r0 + i) * HWID + j0 + c0]) = v;
    }
}

// ---------------- fused attention v5: v3b structure + full up-front load burst -----------------
// 1 node/wave, 16384 blocks (TLP of v3b restored). Zero HW barriers: all LDS wave-private,
// sync via compiler-only wave_barrier (validated correct in v4 run). EVERY global load the
// node needs is issued once, up front, into write-once registers:
//   - 9x float4 stage (rows 0:240 of the 9 neighbors)
//   - 8  f/g scalars
//   - 36 phase-C V values (+ node-invariant c2 folded in)  <- previously a latency-exposed
//     18-gather tail issued AFTER the softmax barrier; now covered by phases A+B
//   - cc / bias scalars
// No register array is rewritten (v4's spill cause); dynamic row indices use __shfl not
// runtime-indexed arrays (rule #20).

__device__ __forceinline__ void wsync() {
    asm volatile("" ::: "memory");
    __builtin_amdgcn_wave_barrier();
    asm volatile("" ::: "memory");
}

__global__ __launch_bounds__(128) void k_attn(const float* __restrict__ ws,
                                              const float* __restrict__ Hbuf,
                                              const int* __restrict__ nbr,
                                              const float* __restrict__ outb,
                                              const float* __restrict__ bvec,
                                              float* __restrict__ u,
                                              int l) {
    __shared__ __align__(16) float sS[2][9][242];  // wave-private: h | hG1 | hG2
    __shared__ float sP[2][2][9][9];               // wave-private scores
    int tid = threadIdx.x;
    int wave = tid >> 6, lane = tid & 63;
    float (*sSw)[242] = sS[wave];
    float (*sPw)[9][9] = sP[wave];
    int n = blockIdx.x * 2 + wave;

    int li = (lane < 9) ? lane : 8;
    int nv = nbr[n * 9 + li];

    // ---------------- load burst ----------------
    // 1) stage: 9 float4 per lane, coalesced over rows 0:240
    float4 st0, st1, st2, st3, st4, st5, st6, st7, st8;
    {
        #define LD_ST(J, DST)                                               \
        {   int i = lane + 64 * (J);                                        \
            int row = i / 60, c4 = i - row * 60;                            \
            int r = __shfl(nv, row);                                        \
            if (i < 540) DST = *(const float4*)(Hbuf + (size_t)r * HWID + c4 * 4); \
            else DST = make_float4(0.f,0.f,0.f,0.f); }
        LD_ST(0, st0) LD_ST(1, st1) LD_ST(2, st2) LD_ST(3, st3) LD_ST(4, st4)
        LD_ST(5, st5) LD_ST(6, st6) LD_ST(7, st7) LD_ST(8, st8)
        #undef LD_ST
    }

    // 2) f/g scalars for score pairs
    int pp2 = (lane < 17) ? (lane + 64) : 80;
    int s1 = lane / 9, t1 = lane - s1 * 9;
    int s2 = pp2 / 9, t2 = pp2 - s2 * 9;
    int rs1 = __shfl(nv, s1), rt1 = __shfl(nv, t1);
    int rs2 = __shfl(nv, s2), rt2 = __shfl(nv, t2);
    const float* pS1 = Hbuf + (size_t)rs1 * HWID;
    const float* pT1 = Hbuf + (size_t)rt1 * HWID;
    const float* pS2 = Hbuf + (size_t)rs2 * HWID;
    const float* pT2 = Hbuf + (size_t)rt2 * HWID;
    float f1a = pS1[240 + t1], g1a = pT1[249 + s1];
    float f2a = pS1[258 + t1], g2a = pT1[267 + s1];
    float f1b = pS2[240 + t2], g1b = pT2[249 + s2];
    float f2b = pS2[258 + t2], g2b = pT2[267 + s2];

    // 3) phase-C V prefetch (+ node-invariant c2 folded in)
    //    iter-1: f = lane (all 64 lanes); iter-2: f = lane+64 (lanes 0..15, clamped else)
    const float* c2a = ws + OFF_C2 + (l*2)*720;
    const float* c2b = c2a + 720;
    int fB = (lane < 16) ? (lane + 64) : 79;
    float va0[9], va1[9], vb0[9], vb1[9];
    #pragma unroll
    for (int t = 0; t < 9; ++t) {
        int r = __shfl(nv, t);
        const float* rowp = Hbuf + (size_t)r * HWID + 280;
        va0[t] = rowp[lane]      + c2a[t*80 + lane];
        va1[t] = rowp[80 + lane] + c2b[t*80 + lane];
        vb0[t] = rowp[fB]        + c2a[t*80 + fB];
        vb1[t] = rowp[80 + fB]   + c2b[t*80 + fB];
    }

    // 4) cc + bias scalars (L2-hot broadcast)
    const float* ccp = ws + OFF_CC + (l * 2) * 81;
    float cc0a = ccp[lane],  cc1a = ccp[81 + lane];
    float cc0b = ccp[pp2],   cc1b = ccp[81 + pp2];
    float biasA = outb[(l*2)*89 + lane] + outb[(l*2+1)*89 + lane] + bvec[lane < 80 ? lane : 0];
    float biasB = (lane < 16) ? (outb[(l*2)*89 + fB] + outb[(l*2+1)*89 + fB] + bvec[fB]) : 0.f;

    // ---------------- write stage to LDS (waits only on the 9 oldest loads) ----------------
    {
        #define ST_ST(J, SRC)                                               \
        {   int i = lane + 64 * (J);                                        \
            if (i < 540) {                                                  \
                int row = i / 60, c4 = i - row * 60;                        \
                *(float4*)(&sSw[row][c4 * 4]) = SRC; } }
        ST_ST(0, st0) ST_ST(1, st1) ST_ST(2, st2) ST_ST(3, st3) ST_ST(4, st4)
        ST_ST(5, st5) ST_ST(6, st6) ST_ST(7, st7) ST_ST(8, st8)
        #undef ST_ST
    }
    wsync();

    const float rsE = 1.0f / 9.433981132056603f;  // 1/sqrt(89)
    // ---- phase A: scores, pair 1 (all 64 lanes) ----
    {
        float a0 = 0.f, a1 = 0.f, b0 = 0.f, b1 = 0.f;
        #pragma unroll
        for (int i = 0; i < 20; ++i) {
            float4 hh = *(const float4*)(&sSw[t1][4*i]);
            float4 g1 = *(const float4*)(&sSw[s1][80 + 4*i]);
            float4 g2 = *(const float4*)(&sSw[s1][160 + 4*i]);
            a0 += g1.x*hh.x + g1.y*hh.y; a1 += g1.z*hh.z + g1.w*hh.w;
            b0 += g2.x*hh.x + g2.y*hh.y; b1 += g2.z*hh.z + g2.w*hh.w;
        }
        sPw[0][s1][t1] = (a0 + a1 + f1a + g1a + cc0a) * rsE;
        sPw[1][s1][t1] = (b0 + b1 + f2a + g2a + cc1a) * rsE;
    }
    // ---- phase A: pair 2 (17 lanes) ----
    if (lane < 17) {
        float a0 = 0.f, a1 = 0.f, b0 = 0.f, b1 = 0.f;
        #pragma unroll
        for (int i = 0; i < 20; ++i) {
            float4 hh = *(const float4*)(&sSw[t2][4*i]);
            float4 g1 = *(const float4*)(&sSw[s2][80 + 4*i]);
            float4 g2 = *(const float4*)(&sSw[s2][160 + 4*i]);
            a0 += g1.x*hh.x + g1.y*hh.y; a1 += g1.z*hh.z + g1.w*hh.w;
            b0 += g2.x*hh.x + g2.y*hh.y; b1 += g2.z*hh.z + g2.w*hh.w;
        }
        sPw[0][s2][t2] = (a0 + a1 + f1b + g1b + cc0b) * rsE;
        sPw[1][s2][t2] = (b0 + b1 + f2b + g2b + cc1b) * rsE;
    }
    wsync();

    // ---- phase B: softmax over t (18 rows) ----
    if (lane < 18) {
        int m = lane / 9, s = lane - m*9;
        float row[9]; float mx = -1e30f;
        #pragma unroll
        for (int t = 0; t < 9; ++t) { row[t] = sPw[m][s][t]; mx = fmaxf(mx, row[t]); }
        float sm = 0.f;
        #pragma unroll
        for (int t = 0; t < 9; ++t) { row[t] = __expf(row[t] - mx); sm += row[t]; }
        float inv = 1.f / sm;
        #pragma unroll
        for (int t = 0; t < 9; ++t) sPw[m][s][t] = row[t] * inv;
    }
    wsync();

    // ---- phase C: PV on prefetched registers + base + max + bias ----
    {
        // f = lane
        float acc[9] = {};
        #pragma unroll
        for (int t = 0; t < 9; ++t) {
            float v0 = va0[t], v1 = va1[t];
            #pragma unroll
            for (int s = 0; s < 9; ++s) acc[s] += sPw[0][s][t] * v0 + sPw[1][s][t] * v1;
        }
        float mx = -1e30f;
        #pragma unroll
        for (int s = 0; s < 9; ++s) mx = fmaxf(mx, acc[s] + sSw[s][lane]);
        u[(size_t)n*80 + lane] = mx + biasA;
    }
    if (lane < 16) {
        // f = lane + 64
        float acc[9] = {};
        #pragma unroll
        for (int t = 0; t < 9; ++t) {
            float v0 = vb0[t], v1 = vb1[t];
            #pragma unroll
            for (int s = 0; s < 9; ++s) acc[s] += sPw[0][s][t] * v0 + sPw[1][s][t] * v1;
        }
        float mx = -1e30f;
        #pragma unroll
        for (int s = 0; s < 9; ++s) mx = fmaxf(mx, acc[s] + sSw[s][fB]);
        u[(size_t)n*80 + fB] = mx + biasB;
    }
}

__global__ __launch_bounds__(256) void k_colreduce(const float* __restrict__ u, float* __restrict__ stats) {
    __shared__ float ps[3][80], ps2[3][80];
    int tid = threadIdx.x;
    int c = tid % 80, rg = tid / 80;
    if (rg < 3) {
        float s = 0.f, s2 = 0.f;
        int rbase = blockIdx.x * 48 + rg * 16;
        for (int i = 0; i < 16; ++i) {
            int rw = rbase + i;
            if (rw < NN) {
                float v = u[(size_t)rw*80 + c];
                s += v; s2 += v*v;
            }
        }
        ps[rg][c] = s; ps2[rg][c] = s2;
    }
    __syncthreads();
    if (tid < 80) {
        atomicAdd(&stats[tid],      ps[0][tid] + ps[1][tid] + ps[2][tid]);
        atomicAdd(&stats[80 + tid], ps2[0][tid] + ps2[1][tid] + ps2[2][tid]);
    }
}

__global__ __launch_bounds__(128) void k_normscale(const float* __restrict__ stats, float* __restrict__ ms) {
    __shared__ float red[80];
    int t = threadIdx.x;
    if (t < 80) {
        float mean = stats[t] * (1.0f / (float)NN);
        ms[t] = mean;
        red[t] = stats[80 + t] - (float)NN * mean * mean;
    }
    __syncthreads();
    if (t == 0) {
        float ss = 0.f;
        for (int i = 0; i < 80; ++i) ss += red[i];
        ms[80] = 1.0f / sqrtf(1e-5f + ss * (1.0f / (float)NN));
    }
}

__global__ __launch_bounds__(256) void k_final(const float* __restrict__ x,
                                               const float* __restrict__ u2,
                                               const float* __restrict__ ms,
                                               float* __restrict__ out) {
    int g = blockIdx.x * 256 + threadIdx.x;
    int n = g / 80, f = g % 80;
    float scale0 = ms[80];
    float v = fmaxf(0.f, (u2[g] - ms[f]) * scale0);
    float o = x[(size_t)n*82 + f] + v;
    if (f == 79 && (o > 1.0f || o < -1.0f)) o = 0.f;
    out[g] = o * 0.5f;
}

extern "C" void kernel_launch(void* const* d_in, const int* in_sizes, int n_in,
                              void* d_out, int out_size, void* d_ws, size_t ws_size,
                              hipStream_t stream) {
    const float* x    = (const float*)d_in[0];
    const float* W1   = (const float*)d_in[1];
    const float* b1   = (const float*)d_in[2];
    const float* W2   = (const float*)d_in[3];
    const float* b2   = (const float*)d_in[4];
    const float* qkvw = (const float*)d_in[5];
    const float* qkvb = (const float*)d_in[6];
    const float* outw = (const float*)d_in[7];
    const float* outb = (const float*)d_in[8];
    const int*   nbr  = (const int*)d_in[9];
    float* ws = (float*)d_ws;
    float* out = (float*)d_out;

    float* H = ws + OFF_H;
    float* u = ws + OFF_U;

    hipMemsetAsync(ws + OFF_STATS, 0, 320 * sizeof(float), stream);
    k_prep_small<<<dim3(59, 4), 256, 0, stream>>>(qkvw, qkvb, outw, ws);
    k_prep_cw<<<dim3(144, 2), 256, 0, stream>>>(W1, W2, ws);

    k_gemm<82, false><<<dim3(512, 7), 256, 0, stream>>>(x, ws + OFF_CW, H, nullptr);
    k_attn<<<16384, 128, 0, stream>>>(ws, H, nbr, outb, b1, u, 0);
    k_colreduce<<<683, 256, 0, stream>>>(u, ws + OFF_STATS);
    k_normscale<<<1, 128, 0, stream>>>(ws + OFF_STATS, ws + OFF_MS);

    k_gemm<80, true><<<dim3(512, 7), 256, 0, stream>>>(u, ws + OFF_CW + 82*448, H, ws + OFF_MS);
    k_attn<<<16384, 128, 0, stream>>>(ws, H, nbr, outb, b2, u, 1);
    k_colreduce<<<683, 256, 0, stream>>>(u, ws + OFF_STATS + 160);
    k_normscale<<<1, 128, 0, stream>>>(ws + OFF_STATS + 160, ws + OFF_MS + 96);

    k_final<<<10240, 256, 0, stream>>>(x, u, ws + OFF_MS + 96, out);
}

// Round 3
// 939.711 us; speedup vs baseline: 1.4833x; 1.0355x over previous
//
#include <hip/hip_runtime.h>

#define NN 32768
#define HWID 448
// H cols: 0:80 h | 80:160 hG1 | 160:240 hG2 | 240:249 f1 | 249:258 g1 | 258:267 f2 | 267:276 g2 |
//         276:280 pad | 280:360 hvo1 | 360:440 hvo2 | 440:448 pad

// ---- workspace float offsets ----
#define OFF_G     0
#define OFF_M     25600
#define OFF_FF    51200
#define OFF_FG    54080
#define OFF_CC    56960
#define OFF_C2    57284
#define OFF_CW    60164
#define OFF_STATS 133636
#define OFF_MS    133956
#define OFF_H     134148
#define OFF_U     14814212

__global__ __launch_bounds__(256) void k_prep_small(const float* __restrict__ qkvw,
                                                    const float* __restrict__ qkvb,
                                                    const float* __restrict__ outw,
                                                    float* __restrict__ ws) {
    int combo = blockIdx.y;
    int e = blockIdx.x * 256 + threadIdx.x;
    const float* Wq = qkvw + combo * 267 * 89;
    const float* Wk = Wq + 89 * 89;
    const float* Wv = Wq + 178 * 89;
    const float* bq = qkvb + combo * 267;
    const float* bk = bq + 89;
    const float* bv = bq + 178;
    const float* Wo = outw + combo * 89 * 89;
    if (e < 6400) {
        int a = e / 80, b = e % 80;
        float s = 0.f;
        for (int j = 0; j < 89; ++j) s += Wq[j*89+a] * Wk[j*89+b];
        ws[OFF_G + combo*6400 + e] = s;
    } else if (e < 12800) {
        int e2 = e - 6400; int f = e2 / 80, c = e2 % 80;
        float s = 0.f;
        for (int j = 0; j < 89; ++j) s += Wo[f*89+j] * Wv[j*89+c];
        ws[OFF_M + combo*6400 + e2] = s;
    } else if (e < 13520) {
        int e3 = e - 12800; int a = e3 / 9, t = e3 % 9;
        float s = 0.f;
        for (int j = 0; j < 89; ++j) s += Wq[j*89+a] * (Wk[j*89+80+t] + bk[j]);
        ws[OFF_FF + combo*720 + e3] = s;
    } else if (e < 14240) {
        int e4 = e - 13520; int a = e4 / 9, si = e4 % 9;
        float s = 0.f;
        for (int j = 0; j < 89; ++j) s += Wk[j*89+a] * (Wq[j*89+80+si] + bq[j]);
        ws[OFF_FG + combo*720 + e4] = s;
    } else if (e < 14321) {
        int e5 = e - 14240; int si = e5 / 9, t = e5 % 9;
        float s = 0.f;
        for (int j = 0; j < 89; ++j) s += (Wq[j*89+80+si] + bq[j]) * (Wk[j*89+80+t] + bk[j]);
        ws[OFF_CC + combo*81 + e5] = s;
    } else if (e < 15041) {
        int e6 = e - 14321; int t = e6 / 80, f = e6 % 80;
        float s = 0.f;
        for (int j = 0; j < 89; ++j) s += Wo[f*89+j] * (Wv[j*89+80+t] + bv[j]);
        ws[OFF_C2 + combo*720 + e6] = s;
    }
}

__global__ __launch_bounds__(256) void k_prep_cw(const float* __restrict__ W1,
                                                 const float* __restrict__ W2,
                                                 float* __restrict__ ws) {
    int l = blockIdx.y;
    int e = blockIdx.x * 256 + threadIdx.x;
    if (e >= 82 * 448) return;
    int k = e / 448, j = e % 448;
    int K = (l == 0) ? 82 : 80;
    float val = 0.f;
    if (k < K) {
        const float* Wr = ((l == 0) ? W1 : W2) + k * 80;
        if (j < 80) {
            val = Wr[j];
        } else if (j < 240) {
            int m = (j - 80) / 80, col = (j - 80) % 80;
            const float* G = ws + OFF_G + (l*2+m)*6400;
            float s = 0.f;
            for (int c = 0; c < 80; ++c) s += Wr[c] * G[c*80 + col];
            val = s;
        } else if (j < 276) {
            int q = j - 240; int m = q / 18; int qq = q % 18;
            int combo = l*2 + m;
            if (qq < 9) {
                const float* Ff = ws + OFF_FF + combo*720;
                float s = 0.f;
                for (int c = 0; c < 80; ++c) s += Wr[c] * Ff[c*9 + qq];
                val = s;
            } else {
                const float* Fg = ws + OFF_FG + combo*720;
                float s = 0.f;
                for (int c = 0; c < 80; ++c) s += Wr[c] * Fg[c*9 + qq - 9];
                val = s;
            }
        } else if (j >= 280 && j < 440) {
            int m = (j - 280) / 80, f = (j - 280) % 80;
            const float* M = ws + OFF_M + (l*2+m)*6400 + f*80;
            float s = 0.f;
            for (int c = 0; c < 80; ++c) s += Wr[c] * M[c];
            val = s;
        }
    }
    ws[OFF_CW + (size_t)l*82*448 + e] = val;
}

template<int K, bool TRANS>
__global__ __launch_bounds__(256) void k_gemm(const float* __restrict__ A,
                                              const float* __restrict__ CW,
                                              float* __restrict__ H,
                                              const float* __restrict__ ms) {
    __shared__ __align__(16) float AsT[K][72];
    __shared__ __align__(16) float Bs[K][68];
    int tid = threadIdx.x;
    int n0 = blockIdx.x * 64;
    int j0 = blockIdx.y * 64;
    float scale0 = 0.f;
    if constexpr (TRANS) scale0 = ms[80];
    for (int idx = tid; idx < 64 * K; idx += 256) {
        int r = idx / K, k = idx - r * K;
        float v = A[(size_t)(n0 + r) * K + k];
        if constexpr (TRANS) v = fmaxf(0.f, (v - ms[k]) * scale0);
        AsT[k][r] = v;
    }
    for (int idx = tid; idx < K * 64; idx += 256) {
        int k = idx >> 6, c = idx & 63;
        Bs[k][c] = CW[k * 448 + j0 + c];
    }
    __syncthreads();
    int r0 = (tid >> 4) * 4, c0 = (tid & 15) * 4;
    float acc[4][4] = {};
    for (int k = 0; k < K; ++k) {
        float4 a4 = *(const float4*)(&AsT[k][r0]);
        float4 b4 = *(const float4*)(&Bs[k][c0]);
        acc[0][0] += a4.x*b4.x; acc[0][1] += a4.x*b4.y; acc[0][2] += a4.x*b4.z; acc[0][3] += a4.x*b4.w;
        acc[1][0] += a4.y*b4.x; acc[1][1] += a4.y*b4.y; acc[1][2] += a4.y*b4.z; acc[1][3] += a4.y*b4.w;
        acc[2][0] += a4.z*b4.x; acc[2][1] += a4.z*b4.y; acc[2][2] += a4.z*b4.z; acc[2][3] += a4.z*b4.w;
        acc[3][0] += a4.w*b4.x; acc[3][1] += a4.w*b4.y; acc[3][2] += a4.w*b4.z; acc[3][3] += a4.w*b4.w;
    }
    for (int i = 0; i < 4; ++i) {
        float4 v = make_float4(acc[i][0], acc[i][1], acc[i][2], acc[i][3]);
        *(float4*)(&H[(size_t)(n0 + r0 + i) * HWID + j0 + c0]) = v;
    }
}

// ---------------- fused attention v6: v3b structure + batched stage + V-only prefetch ----------
// Changes vs v3b (proven 191 us):
//  (1) stage loop manually unrolled: 9 batched global loads -> ONE vmcnt wait -> 9 ds_writes
//      (v3b's strided loop risked per-iteration load->wait->write serialization)
//  (2) f/g + phase-C V gathers issued AFTER the stage ds_writes (stage regs dead first ->
//      peak VGPR stays ~110 < 128 budget; v5's all-at-once burst forced the compiler to
//      serialize into batches at an 88-VGPR budget: VALUBusy halved, time doubled)
//  (3) wave-private wsync instead of __syncthreads (no forced vmcnt(0) drain at barriers;
//      correctness of this sync validated in v4/v5 runs) -> V loads fly during phases A+B
// c2/cc/bias loads stay inline (L2-hot, ~200cy) — one change-class per round.

__device__ __forceinline__ void wsync() {
    asm volatile("" ::: "memory");
    __builtin_amdgcn_wave_barrier();
    asm volatile("" ::: "memory");
}

__global__ __launch_bounds__(128) void k_attn(const float* __restrict__ ws,
                                              const float* __restrict__ Hbuf,
                                              const int* __restrict__ nbr,
                                              const float* __restrict__ outb,
                                              const float* __restrict__ bvec,
                                              float* __restrict__ u,
                                              int l) {
    __shared__ __align__(16) float sS[2][9][242];  // wave-private: h | hG1 | hG2
    __shared__ float sP[2][2][9][9];               // wave-private scores
    int tid = threadIdx.x;
    int wave = tid >> 6, lane = tid & 63;
    float (*sSw)[242] = sS[wave];
    float (*sPw)[9][9] = sP[wave];
    int n = blockIdx.x * 2 + wave;

    int li = (lane < 9) ? lane : 8;
    int nv = nbr[n * 9 + li];

    int pp2 = (lane < 17) ? (lane + 64) : 80;
    int s1 = lane / 9, t1 = lane - s1 * 9;
    int s2 = pp2 / 9, t2 = pp2 - s2 * 9;

    // ---- stage: 9 batched float4 loads (rows 0:240 of the 9 neighbors) ----
    float4 st0, st1, st2, st3, st4, st5, st6, st7, st8;
    {
        #define LD_ST(J, DST)                                                   \
        {   int i = lane + 64 * (J);                                            \
            int row = i / 60, c4 = i - row * 60;                                \
            int r = __shfl(nv, row);                                            \
            if (i < 540) DST = *(const float4*)(Hbuf + (size_t)r * HWID + c4 * 4); \
            else DST = make_float4(0.f,0.f,0.f,0.f); }
        LD_ST(0, st0) LD_ST(1, st1) LD_ST(2, st2) LD_ST(3, st3) LD_ST(4, st4)
        LD_ST(5, st5) LD_ST(6, st6) LD_ST(7, st7) LD_ST(8, st8)
        #undef LD_ST
    }
    // ---- write stage to LDS: one vmcnt wait covers all 9 loads ----
    {
        #define ST_ST(J, SRC)                                                   \
        {   int i = lane + 64 * (J);                                            \
            if (i < 540) {                                                      \
                int row = i / 60, c4 = i - row * 60;                            \
                *(float4*)(&sSw[row][c4 * 4]) = SRC; } }
        ST_ST(0, st0) ST_ST(1, st1) ST_ST(2, st2) ST_ST(3, st3) ST_ST(4, st4)
        ST_ST(5, st5) ST_ST(6, st6) ST_ST(7, st7) ST_ST(8, st8)
        #undef ST_ST
    }

    // ---- overlap loads: issued now, consumed end-of-A (f/g) and in C (V) ----
    int rs1 = __shfl(nv, s1), rt1 = __shfl(nv, t1);
    int rs2 = __shfl(nv, s2), rt2 = __shfl(nv, t2);
    const float* pS1 = Hbuf + (size_t)rs1 * HWID;
    const float* pT1 = Hbuf + (size_t)rt1 * HWID;
    const float* pS2 = Hbuf + (size_t)rs2 * HWID;
    const float* pT2 = Hbuf + (size_t)rt2 * HWID;
    float f1a = pS1[240 + t1], g1a = pT1[249 + s1];
    float f2a = pS1[258 + t1], g2a = pT1[267 + s1];
    float f1b = pS2[240 + t2], g1b = pT2[249 + s2];
    float f2b = pS2[258 + t2], g2b = pT2[267 + s2];

    int fB = (lane < 16) ? (lane + 64) : 79;
    float va0[9], va1[9], vb0[9], vb1[9];
    #pragma unroll
    for (int t = 0; t < 9; ++t) {
        int r = __shfl(nv, t);
        const float* rowp = Hbuf + (size_t)r * HWID + 280;
        va0[t] = rowp[lane];
        va1[t] = rowp[80 + lane];
        vb0[t] = rowp[fB];
        vb1[t] = rowp[80 + fB];
    }

    // cc + bias (L2-hot broadcast scalars)
    const float* ccp = ws + OFF_CC + (l * 2) * 81;
    float cc0a = ccp[lane],  cc1a = ccp[81 + lane];
    float cc0b = ccp[pp2],   cc1b = ccp[81 + pp2];
    float biasA = outb[(l*2)*89 + lane] + outb[(l*2+1)*89 + lane] + bvec[lane < 80 ? lane : 0];
    float biasB = (lane < 16) ? (outb[(l*2)*89 + fB] + outb[(l*2+1)*89 + fB] + bvec[fB]) : 0.f;

    wsync();

    const float rsE = 1.0f / 9.433981132056603f;  // 1/sqrt(89)
    // ---- phase A: scores, pair 1 (all 64 lanes) ----
    {
        float a0 = 0.f, a1 = 0.f, b0 = 0.f, b1 = 0.f;
        #pragma unroll
        for (int i = 0; i < 20; ++i) {
            float4 hh = *(const float4*)(&sSw[t1][4*i]);
            float4 g1 = *(const float4*)(&sSw[s1][80 + 4*i]);
            float4 g2 = *(const float4*)(&sSw[s1][160 + 4*i]);
            a0 += g1.x*hh.x + g1.y*hh.y; a1 += g1.z*hh.z + g1.w*hh.w;
            b0 += g2.x*hh.x + g2.y*hh.y; b1 += g2.z*hh.z + g2.w*hh.w;
        }
        sPw[0][s1][t1] = (a0 + a1 + f1a + g1a + cc0a) * rsE;
        sPw[1][s1][t1] = (b0 + b1 + f2a + g2a + cc1a) * rsE;
    }
    // ---- phase A: pair 2 (17 lanes) ----
    if (lane < 17) {
        float a0 = 0.f, a1 = 0.f, b0 = 0.f, b1 = 0.f;
        #pragma unroll
        for (int i = 0; i < 20; ++i) {
            float4 hh = *(const float4*)(&sSw[t2][4*i]);
            float4 g1 = *(const float4*)(&sSw[s2][80 + 4*i]);
            float4 g2 = *(const float4*)(&sSw[s2][160 + 4*i]);
            a0 += g1.x*hh.x + g1.y*hh.y; a1 += g1.z*hh.z + g1.w*hh.w;
            b0 += g2.x*hh.x + g2.y*hh.y; b1 += g2.z*hh.z + g2.w*hh.w;
        }
        sPw[0][s2][t2] = (a0 + a1 + f1b + g1b + cc0b) * rsE;
        sPw[1][s2][t2] = (b0 + b1 + f2b + g2b + cc1b) * rsE;
    }
    wsync();

    // ---- phase B: softmax over t (18 rows) ----
    if (lane < 18) {
        int m = lane / 9, s = lane - m*9;
        float row[9]; float mx = -1e30f;
        #pragma unroll
        for (int t = 0; t < 9; ++t) { row[t] = sPw[m][s][t]; mx = fmaxf(mx, row[t]); }
        float sm = 0.f;
        #pragma unroll
        for (int t = 0; t < 9; ++t) { row[t] = __expf(row[t] - mx); sm += row[t]; }
        float inv = 1.f / sm;
        #pragma unroll
        for (int t = 0; t < 9; ++t) sPw[m][s][t] = row[t] * inv;
    }
    wsync();

    // ---- phase C: PV on prefetched V regs (+ inline L2-hot c2) + base + max + bias ----
    const float* c2a = ws + OFF_C2 + (l*2)*720;
    const float* c2b = c2a + 720;
    {
        float acc[9] = {};
        #pragma unroll
        for (int t = 0; t < 9; ++t) {
            float v0 = va0[t] + c2a[t*80 + lane];
            float v1 = va1[t] + c2b[t*80 + lane];
            #pragma unroll
            for (int s = 0; s < 9; ++s) acc[s] += sPw[0][s][t] * v0 + sPw[1][s][t] * v1;
        }
        float mx = -1e30f;
        #pragma unroll
        for (int s = 0; s < 9; ++s) mx = fmaxf(mx, acc[s] + sSw[s][lane]);
        u[(size_t)n*80 + lane] = mx + biasA;
    }
    if (lane < 16) {
        float acc[9] = {};
        #pragma unroll
        for (int t = 0; t < 9; ++t) {
            float v0 = vb0[t] + c2a[t*80 + fB];
            float v1 = vb1[t] + c2b[t*80 + fB];
            #pragma unroll
            for (int s = 0; s < 9; ++s) acc[s] += sPw[0][s][t] * v0 + sPw[1][s][t] * v1;
        }
        float mx = -1e30f;
        #pragma unroll
        for (int s = 0; s < 9; ++s) mx = fmaxf(mx, acc[s] + sSw[s][fB]);
        u[(size_t)n*80 + fB] = mx + biasB;
    }
}

__global__ __launch_bounds__(256) void k_colreduce(const float* __restrict__ u, float* __restrict__ stats) {
    __shared__ float ps[3][80], ps2[3][80];
    int tid = threadIdx.x;
    int c = tid % 80, rg = tid / 80;
    if (rg < 3) {
        float s = 0.f, s2 = 0.f;
        int rbase = blockIdx.x * 48 + rg * 16;
        for (int i = 0; i < 16; ++i) {
            int rw = rbase + i;
            if (rw < NN) {
                float v = u[(size_t)rw*80 + c];
                s += v; s2 += v*v;
            }
        }
        ps[rg][c] = s; ps2[rg][c] = s2;
    }
    __syncthreads();
    if (tid < 80) {
        atomicAdd(&stats[tid],      ps[0][tid] + ps[1][tid] + ps[2][tid]);
        atomicAdd(&stats[80 + tid], ps2[0][tid] + ps2[1][tid] + ps2[2][tid]);
    }
}

__global__ __launch_bounds__(128) void k_normscale(const float* __restrict__ stats, float* __restrict__ ms) {
    __shared__ float red[80];
    int t = threadIdx.x;
    if (t < 80) {
        float mean = stats[t] * (1.0f / (float)NN);
        ms[t] = mean;
        red[t] = stats[80 + t] - (float)NN * mean * mean;
    }
    __syncthreads();
    if (t == 0) {
        float ss = 0.f;
        for (int i = 0; i < 80; ++i) ss += red[i];
        ms[80] = 1.0f / sqrtf(1e-5f + ss * (1.0f / (float)NN));
    }
}

__global__ __launch_bounds__(256) void k_final(const float* __restrict__ x,
                                               const float* __restrict__ u2,
                                               const float* __restrict__ ms,
                                               float* __restrict__ out) {
    int g = blockIdx.x * 256 + threadIdx.x;
    int n = g / 80, f = g % 80;
    float scale0 = ms[80];
    float v = fmaxf(0.f, (u2[g] - ms[f]) * scale0);
    float o = x[(size_t)n*82 + f] + v;
    if (f == 79 && (o > 1.0f || o < -1.0f)) o = 0.f;
    out[g] = o * 0.5f;
}

extern "C" void kernel_launch(void* const* d_in, const int* in_sizes, int n_in,
                              void* d_out, int out_size, void* d_ws, size_t ws_size,
                              hipStream_t stream) {
    const float* x    = (const float*)d_in[0];
    const float* W1   = (const float*)d_in[1];
    const float* b1   = (const float*)d_in[2];
    const float* W2   = (const float*)d_in[3];
    const float* b2   = (const float*)d_in[4];
    const float* qkvw = (const float*)d_in[5];
    const float* qkvb = (const float*)d_in[6];
    const float* outw = (const float*)d_in[7];
    const float* outb = (const float*)d_in[8];
    const int*   nbr  = (const int*)d_in[9];
    float* ws = (float*)d_ws;
    float* out = (float*)d_out;

    float* H = ws + OFF_H;
    float* u = ws + OFF_U;

    hipMemsetAsync(ws + OFF_STATS, 0, 320 * sizeof(float), stream);
    k_prep_small<<<dim3(59, 4), 256, 0, stream>>>(qkvw, qkvb, outw, ws);
    k_prep_cw<<<dim3(144, 2), 256, 0, stream>>>(W1, W2, ws);

    k_gemm<82, false><<<dim3(512, 7), 256, 0, stream>>>(x, ws + OFF_CW, H, nullptr);
    k_attn<<<16384, 128, 0, stream>>>(ws, H, nbr, outb, b1, u, 0);
    k_colreduce<<<683, 256, 0, stream>>>(u, ws + OFF_STATS);
    k_normscale<<<1, 128, 0, stream>>>(ws + OFF_STATS, ws + OFF_MS);

    k_gemm<80, true><<<dim3(512, 7), 256, 0, stream>>>(u, ws + OFF_CW + 82*448, H, ws + OFF_MS);
    k_attn<<<16384, 128, 0, stream>>>(ws, H, nbr, outb, b2, u, 1);
    k_colreduce<<<683, 256, 0, stream>>>(u, ws + OFF_STATS + 160);
    k_normscale<<<1, 128, 0, stream>>>(ws + OFF_STATS + 160, ws + OFF_MS + 96);

    k_final<<<10240, 256, 0, stream>>>(x, u, ws + OFF_MS + 96, out);
}

// Round 4
// 653.064 us; speedup vs baseline: 2.1344x; 1.4389x over previous
//
#include <hip/hip_runtime.h>

#define NN 32768
#define HWID 448
// H cols: 0:80 h | 80:160 hG1 | 160:240 hG2 | 240:249 f1 | 249:258 g1 | 258:267 f2 | 267:276 g2 |
//         276:280 pad | 280:360 hvo1 | 360:440 hvo2 | 440:448 pad

// ---- workspace float offsets ----
#define OFF_G     0
#define OFF_M     25600
#define OFF_FF    51200
#define OFF_FG    54080
#define OFF_CC    56960
#define OFF_C2    57284
#define OFF_CW    60164
#define OFF_STATS 133636
#define OFF_MS    133956
#define OFF_H     134148
#define OFF_U     14814212

__global__ __launch_bounds__(256) void k_prep_small(const float* __restrict__ qkvw,
                                                    const float* __restrict__ qkvb,
                                                    const float* __restrict__ outw,
                                                    float* __restrict__ ws) {
    int combo = blockIdx.y;
    int e = blockIdx.x * 256 + threadIdx.x;
    const float* Wq = qkvw + combo * 267 * 89;
    const float* Wk = Wq + 89 * 89;
    const float* Wv = Wq + 178 * 89;
    const float* bq = qkvb + combo * 267;
    const float* bk = bq + 89;
    const float* bv = bq + 178;
    const float* Wo = outw + combo * 89 * 89;
    if (e < 6400) {
        int a = e / 80, b = e % 80;
        float s = 0.f;
        for (int j = 0; j < 89; ++j) s += Wq[j*89+a] * Wk[j*89+b];
        ws[OFF_G + combo*6400 + e] = s;
    } else if (e < 12800) {
        int e2 = e - 6400; int f = e2 / 80, c = e2 % 80;
        float s = 0.f;
        for (int j = 0; j < 89; ++j) s += Wo[f*89+j] * Wv[j*89+c];
        ws[OFF_M + combo*6400 + e2] = s;
    } else if (e < 13520) {
        int e3 = e - 12800; int a = e3 / 9, t = e3 % 9;
        float s = 0.f;
        for (int j = 0; j < 89; ++j) s += Wq[j*89+a] * (Wk[j*89+80+t] + bk[j]);
        ws[OFF_FF + combo*720 + e3] = s;
    } else if (e < 14240) {
        int e4 = e - 13520; int a = e4 / 9, si = e4 % 9;
        float s = 0.f;
        for (int j = 0; j < 89; ++j) s += Wk[j*89+a] * (Wq[j*89+80+si] + bq[j]);
        ws[OFF_FG + combo*720 + e4] = s;
    } else if (e < 14321) {
        int e5 = e - 14240; int si = e5 / 9, t = e5 % 9;
        float s = 0.f;
        for (int j = 0; j < 89; ++j) s += (Wq[j*89+80+si] + bq[j]) * (Wk[j*89+80+t] + bk[j]);
        ws[OFF_CC + combo*81 + e5] = s;
    } else if (e < 15041) {
        int e6 = e - 14321; int t = e6 / 80, f = e6 % 80;
        float s = 0.f;
        for (int j = 0; j < 89; ++j) s += Wo[f*89+j] * (Wv[j*89+80+t] + bv[j]);
        ws[OFF_C2 + combo*720 + e6] = s;
    }
}

__global__ __launch_bounds__(256) void k_prep_cw(const float* __restrict__ W1,
                                                 const float* __restrict__ W2,
                                                 float* __restrict__ ws) {
    int l = blockIdx.y;
    int e = blockIdx.x * 256 + threadIdx.x;
    if (e >= 82 * 448) return;
    int k = e / 448, j = e % 448;
    int K = (l == 0) ? 82 : 80;
    float val = 0.f;
    if (k < K) {
        const float* Wr = ((l == 0) ? W1 : W2) + k * 80;
        if (j < 80) {
            val = Wr[j];
        } else if (j < 240) {
            int m = (j - 80) / 80, col = (j - 80) % 80;
            const float* G = ws + OFF_G + (l*2+m)*6400;
            float s = 0.f;
            for (int c = 0; c < 80; ++c) s += Wr[c] * G[c*80 + col];
            val = s;
        } else if (j < 276) {
            int q = j - 240; int m = q / 18; int qq = q % 18;
            int combo = l*2 + m;
            if (qq < 9) {
                const float* Ff = ws + OFF_FF + combo*720;
                float s = 0.f;
                for (int c = 0; c < 80; ++c) s += Wr[c] * Ff[c*9 + qq];
                val = s;
            } else {
                const float* Fg = ws + OFF_FG + combo*720;
                float s = 0.f;
                for (int c = 0; c < 80; ++c) s += Wr[c] * Fg[c*9 + qq - 9];
                val = s;
            }
        } else if (j >= 280 && j < 440) {
            int m = (j - 280) / 80, f = (j - 280) % 80;
            const float* M = ws + OFF_M + (l*2+m)*6400 + f*80;
            float s = 0.f;
            for (int c = 0; c < 80; ++c) s += Wr[c] * M[c];
            val = s;
        }
    }
    ws[OFF_CW + (size_t)l*82*448 + e] = val;
}

template<int K, bool TRANS>
__global__ __launch_bounds__(256) void k_gemm(const float* __restrict__ A,
                                              const float* __restrict__ CW,
                                              float* __restrict__ H,
                                              const float* __restrict__ ms) {
    __shared__ __align__(16) float AsT[K][72];
    __shared__ __align__(16) float Bs[K][68];
    int tid = threadIdx.x;
    int n0 = blockIdx.x * 64;
    int j0 = blockIdx.y * 64;
    float scale0 = 0.f;
    if constexpr (TRANS) scale0 = ms[80];
    for (int idx = tid; idx < 64 * K; idx += 256) {
        int r = idx / K, k = idx - r * K;
        float v = A[(size_t)(n0 + r) * K + k];
        if constexpr (TRANS) v = fmaxf(0.f, (v - ms[k]) * scale0);
        AsT[k][r] = v;
    }
    for (int idx = tid; idx < K * 64; idx += 256) {
        int k = idx >> 6, c = idx & 63;
        Bs[k][c] = CW[k * 448 + j0 + c];
    }
    __syncthreads();
    int r0 = (tid >> 4) * 4, c0 = (tid & 15) * 4;
    float acc[4][4] = {};
    for (int k = 0; k < K; ++k) {
        float4 a4 = *(const float4*)(&AsT[k][r0]);
        float4 b4 = *(const float4*)(&Bs[k][c0]);
        acc[0][0] += a4.x*b4.x; acc[0][1] += a4.x*b4.y; acc[0][2] += a4.x*b4.z; acc[0][3] += a4.x*b4.w;
        acc[1][0] += a4.y*b4.x; acc[1][1] += a4.y*b4.y; acc[1][2] += a4.y*b4.z; acc[1][3] += a4.y*b4.w;
        acc[2][0] += a4.z*b4.x; acc[2][1] += a4.z*b4.y; acc[2][2] += a4.z*b4.z; acc[2][3] += a4.z*b4.w;
        acc[3][0] += a4.w*b4.x; acc[3][1] += a4.w*b4.y; acc[3][2] += a4.w*b4.z; acc[3][3] += a4.w*b4.w;
    }
    for (int i = 0; i < 4; ++i) {
        float4 v = make_float4(acc[i][0], acc[i][1], acc[i][2], acc[i][3]);
        *(float4*)(&H[(size_t)(n0 + r0 + i) * HWID + j0 + c0]) = v;
    }
}

// ---------------- fused attention v7: v3b + V staged into LDS in the single burst -------------
// v3b verbatim EXCEPT: the stage loop also gathers global cols 280:440 (the phase-C V rows)
// into LDS cols 240:400 (stride 404). Mechanism: all node gather loads are issued in ONE
// 15-round burst before __syncthreads; the barrier's mandatory vmcnt(0) drain merges the
// V-gather latency into the stage latency (1 exposure instead of 2 serialized), and the
// compiler CANNOT sink loads past a barrier fence nor reschedule LDS-destined data for
// register pressure (v5/v6 failure mode). Phase C is then LDS-only.
// Cost: LDS 19.0->30.3 KB/block (5 blocks/CU theoretical, was 8) — acceptable because v6
// proved occupancy is not the binding resource (45% occ, 2x slower).

__global__ __launch_bounds__(128) void k_attn(const float* __restrict__ ws,
                                              const float* __restrict__ Hbuf,
                                              const int* __restrict__ nbr,
                                              const float* __restrict__ outb,
                                              const float* __restrict__ bvec,
                                              float* __restrict__ u,
                                              int l) {
    __shared__ __align__(16) float sS[2][9][404];  // 0:240 h|hG1|hG2, 240:400 V(m=0,1), wave-private
    __shared__ float sP[2][2][9][9];
    __shared__ float sCC[2][81];
    int tid = threadIdx.x;
    int wave = tid >> 6, lane = tid & 63;
    int n = blockIdx.x * 2 + wave;
    int nv = nbr[n * 9 + (lane < 9 ? lane : 8)];
    int rr[9];
    #pragma unroll
    for (int s = 0; s < 9; ++s) rr[s] = __shfl(nv, s);

    // pair-1 (pp = lane < 81 always) f/g register prefetch
    int s1 = lane / 9, t1 = lane - s1 * 9;
    const float* rowS1 = Hbuf + (size_t)rr[s1] * HWID;
    const float* rowT1 = Hbuf + (size_t)rr[t1] * HWID;
    float f1a = rowS1[240 + t1], g1a = rowT1[249 + s1];
    float f2a = rowS1[258 + t1], g2a = rowT1[267 + s1];
    // pair-2 (pp2 = lane+64, valid for lane < 17)
    int pp2 = (lane < 17) ? (lane + 64) : 80;
    int s2 = pp2 / 9, t2 = pp2 - s2 * 9;
    const float* rowS2 = Hbuf + (size_t)rr[s2] * HWID;
    const float* rowT2 = Hbuf + (size_t)rr[t2] * HWID;
    float f1b = rowS2[240 + t2], g1b = rowT2[249 + s2];
    float f2b = rowS2[258 + t2], g2b = rowT2[267 + s2];

    // cc -> LDS (block-shared)
    for (int i = tid; i < 162; i += 128) sCC[0][i] = ws[OFF_CC + (l*2)*81 + i];

    // stage 9 rows x 100 float4 (cols 0:240 -> LDS 0:240, cols 280:440 -> LDS 240:400)
    for (int i = lane; i < 900; i += 64) {
        int row = i / 100, c = i - row * 100;
        int gc = (c < 60) ? (c * 4) : (280 + (c - 60) * 4);
        int lc = (c < 60) ? (c * 4) : (240 + (c - 60) * 4);
        float4 v = *(const float4*)(Hbuf + (size_t)rr[row] * HWID + gc);
        *(float4*)(&sS[wave][row][lc]) = v;
    }
    __syncthreads();

    const float rsE = 1.0f / 9.433981132056603f;  // 1/sqrt(89)
    // phase A: pair 1
    {
        float a0 = 0.f, a1 = 0.f, b0 = 0.f, b1 = 0.f;
        #pragma unroll
        for (int i = 0; i < 20; ++i) {
            float4 hh = *(const float4*)(&sS[wave][t1][4*i]);
            float4 g1 = *(const float4*)(&sS[wave][s1][80 + 4*i]);
            float4 g2 = *(const float4*)(&sS[wave][s1][160 + 4*i]);
            a0 += g1.x*hh.x + g1.y*hh.y; a1 += g1.z*hh.z + g1.w*hh.w;
            b0 += g2.x*hh.x + g2.y*hh.y; b1 += g2.z*hh.z + g2.w*hh.w;
        }
        sP[wave][0][s1][t1] = (a0 + a1 + f1a + g1a + sCC[0][lane]) * rsE;
        sP[wave][1][s1][t1] = (b0 + b1 + f2a + g2a + sCC[1][lane]) * rsE;
    }
    // phase A: pair 2 (17 lanes)
    if (lane < 17) {
        float a0 = 0.f, a1 = 0.f, b0 = 0.f, b1 = 0.f;
        #pragma unroll
        for (int i = 0; i < 20; ++i) {
            float4 hh = *(const float4*)(&sS[wave][t2][4*i]);
            float4 g1 = *(const float4*)(&sS[wave][s2][80 + 4*i]);
            float4 g2 = *(const float4*)(&sS[wave][s2][160 + 4*i]);
            a0 += g1.x*hh.x + g1.y*hh.y; a1 += g1.z*hh.z + g1.w*hh.w;
            b0 += g2.x*hh.x + g2.y*hh.y; b1 += g2.z*hh.z + g2.w*hh.w;
        }
        sP[wave][0][s2][t2] = (a0 + a1 + f1b + g1b + sCC[0][pp2]) * rsE;
        sP[wave][1][s2][t2] = (b0 + b1 + f2b + g2b + sCC[1][pp2]) * rsE;
    }
    __syncthreads();
    // phase B: softmax over t (18 rows per node)
    if (lane < 18) {
        int m = lane / 9, s = lane - m*9;
        float row[9]; float mx = -1e30f;
        #pragma unroll
        for (int t = 0; t < 9; ++t) { row[t] = sP[wave][m][s][t]; mx = fmaxf(mx, row[t]); }
        float sm = 0.f;
        #pragma unroll
        for (int t = 0; t < 9; ++t) { row[t] = __expf(row[t] - mx); sm += row[t]; }
        float inv = 1.f / sm;
        #pragma unroll
        for (int t = 0; t < 9; ++t) sP[wave][m][s][t] = row[t] * inv;
    }
    __syncthreads();
    // phase C: PV (V from LDS) + base(LDS) + max + bias
    for (int f = lane; f < 80; f += 64) {
        float acc[9] = {};
        #pragma unroll
        for (int m = 0; m < 2; ++m) {
            const float* c2 = ws + OFF_C2 + (l*2+m)*720;
            #pragma unroll
            for (int t = 0; t < 9; ++t) {
                float vv = sS[wave][t][240 + m*80 + f] + c2[t*80 + f];
                #pragma unroll
                for (int s = 0; s < 9; ++s) acc[s] += sP[wave][m][s][t] * vv;
            }
        }
        float mx = -1e30f;
        #pragma unroll
        for (int s = 0; s < 9; ++s) mx = fmaxf(mx, acc[s] + sS[wave][s][f]);
        float bias = outb[(l*2)*89 + f] + outb[(l*2+1)*89 + f] + bvec[f];
        u[(size_t)n*80 + f] = mx + bias;
    }
}

__global__ __launch_bounds__(256) void k_colreduce(const float* __restrict__ u, float* __restrict__ stats) {
    __shared__ float ps[3][80], ps2[3][80];
    int tid = threadIdx.x;
    int c = tid % 80, rg = tid / 80;
    if (rg < 3) {
        float s = 0.f, s2 = 0.f;
        int rbase = blockIdx.x * 48 + rg * 16;
        for (int i = 0; i < 16; ++i) {
            int rw = rbase + i;
            if (rw < NN) {
                float v = u[(size_t)rw*80 + c];
                s += v; s2 += v*v;
            }
        }
        ps[rg][c] = s; ps2[rg][c] = s2;
    }
    __syncthreads();
    if (tid < 80) {
        atomicAdd(&stats[tid],      ps[0][tid] + ps[1][tid] + ps[2][tid]);
        atomicAdd(&stats[80 + tid], ps2[0][tid] + ps2[1][tid] + ps2[2][tid]);
    }
}

__global__ __launch_bounds__(128) void k_normscale(const float* __restrict__ stats, float* __restrict__ ms) {
    __shared__ float red[80];
    int t = threadIdx.x;
    if (t < 80) {
        float mean = stats[t] * (1.0f / (float)NN);
        ms[t] = mean;
        red[t] = stats[80 + t] - (float)NN * mean * mean;
    }
    __syncthreads();
    if (t == 0) {
        float ss = 0.f;
        for (int i = 0; i < 80; ++i) ss += red[i];
        ms[80] = 1.0f / sqrtf(1e-5f + ss * (1.0f / (float)NN));
    }
}

__global__ __launch_bounds__(256) void k_final(const float* __restrict__ x,
                                               const float* __restrict__ u2,
                                               const float* __restrict__ ms,
                                               float* __restrict__ out) {
    int g = blockIdx.x * 256 + threadIdx.x;
    int n = g / 80, f = g % 80;
    float scale0 = ms[80];
    float v = fmaxf(0.f, (u2[g] - ms[f]) * scale0);
    float o = x[(size_t)n*82 + f] + v;
    if (f == 79 && (o > 1.0f || o < -1.0f)) o = 0.f;
    out[g] = o * 0.5f;
}

extern "C" void kernel_launch(void* const* d_in, const int* in_sizes, int n_in,
                              void* d_out, int out_size, void* d_ws, size_t ws_size,
                              hipStream_t stream) {
    const float* x    = (const float*)d_in[0];
    const float* W1   = (const float*)d_in[1];
    const float* b1   = (const float*)d_in[2];
    const float* W2   = (const float*)d_in[3];
    const float* b2   = (const float*)d_in[4];
    const float* qkvw = (const float*)d_in[5];
    const float* qkvb = (const float*)d_in[6];
    const float* outw = (const float*)d_in[7];
    const float* outb = (const float*)d_in[8];
    const int*   nbr  = (const int*)d_in[9];
    float* ws = (float*)d_ws;
    float* out = (float*)d_out;

    float* H = ws + OFF_H;
    float* u = ws + OFF_U;

    hipMemsetAsync(ws + OFF_STATS, 0, 320 * sizeof(float), stream);
    k_prep_small<<<dim3(59, 4), 256, 0, stream>>>(qkvw, qkvb, outw, ws);
    k_prep_cw<<<dim3(144, 2), 256, 0, stream>>>(W1, W2, ws);

    k_gemm<82, false><<<dim3(512, 7), 256, 0, stream>>>(x, ws + OFF_CW, H, nullptr);
    k_attn<<<16384, 128, 0, stream>>>(ws, H, nbr, outb, b1, u, 0);
    k_colreduce<<<683, 256, 0, stream>>>(u, ws + OFF_STATS);
    k_normscale<<<1, 128, 0, stream>>>(ws + OFF_STATS, ws + OFF_MS);

    k_gemm<80, true><<<dim3(512, 7), 256, 0, stream>>>(u, ws + OFF_CW + 82*448, H, ws + OFF_MS);
    k_attn<<<16384, 128, 0, stream>>>(ws, H, nbr, outb, b2, u, 1);
    k_colreduce<<<683, 256, 0, stream>>>(u, ws + OFF_STATS + 160);
    k_normscale<<<1, 128, 0, stream>>>(ws + OFF_STATS + 160, ws + OFF_MS + 96);

    k_final<<<10240, 256, 0, stream>>>(x, u, ws + OFF_MS + 96, out);
}

// Round 5
// 523.143 us; speedup vs baseline: 2.6645x; 1.2483x over previous
//
#include <hip/hip_runtime.h>

#define NN 32768
#define HWID 448
// H cols: 0:80 h | 80:160 hG1 | 160:240 hG2 | 240:249 f1 | 249:258 g1 | 258:267 f2 | 267:276 g2 |
//         276:280 pad | 280:360 hvo1 | 360:440 hvo2 | 440:448 pad

// ---- workspace float offsets ----
#define OFF_G     0
#define OFF_M     25600
#define OFF_FF    51200
#define OFF_FG    54080
#define OFF_CC    56960
#define OFF_C2    57284
#define OFF_CW    60164
#define OFF_STATS 133636
#define OFF_MS    133956
#define OFF_H     134148
#define OFF_U     14814212

__global__ __launch_bounds__(256) void k_prep_small(const float* __restrict__ qkvw,
                                                    const float* __restrict__ qkvb,
                                                    const float* __restrict__ outw,
                                                    float* __restrict__ ws) {
    int combo = blockIdx.y;
    int e = blockIdx.x * 256 + threadIdx.x;
    const float* Wq = qkvw + combo * 267 * 89;
    const float* Wk = Wq + 89 * 89;
    const float* Wv = Wq + 178 * 89;
    const float* bq = qkvb + combo * 267;
    const float* bk = bq + 89;
    const float* bv = bq + 178;
    const float* Wo = outw + combo * 89 * 89;
    if (e < 6400) {
        int a = e / 80, b = e % 80;
        float s = 0.f;
        for (int j = 0; j < 89; ++j) s += Wq[j*89+a] * Wk[j*89+b];
        ws[OFF_G + combo*6400 + e] = s;
    } else if (e < 12800) {
        int e2 = e - 6400; int f = e2 / 80, c = e2 % 80;
        float s = 0.f;
        for (int j = 0; j < 89; ++j) s += Wo[f*89+j] * Wv[j*89+c];
        ws[OFF_M + combo*6400 + e2] = s;
    } else if (e < 13520) {
        int e3 = e - 12800; int a = e3 / 9, t = e3 % 9;
        float s = 0.f;
        for (int j = 0; j < 89; ++j) s += Wq[j*89+a] * (Wk[j*89+80+t] + bk[j]);
        ws[OFF_FF + combo*720 + e3] = s;
    } else if (e < 14240) {
        int e4 = e - 13520; int a = e4 / 9, si = e4 % 9;
        float s = 0.f;
        for (int j = 0; j < 89; ++j) s += Wk[j*89+a] * (Wq[j*89+80+si] + bq[j]);
        ws[OFF_FG + combo*720 + e4] = s;
    } else if (e < 14321) {
        int e5 = e - 14240; int si = e5 / 9, t = e5 % 9;
        float s = 0.f;
        for (int j = 0; j < 89; ++j) s += (Wq[j*89+80+si] + bq[j]) * (Wk[j*89+80+t] + bk[j]);
        ws[OFF_CC + combo*81 + e5] = s;
    } else if (e < 15041) {
        int e6 = e - 14321; int t = e6 / 80, f = e6 % 80;
        float s = 0.f;
        for (int j = 0; j < 89; ++j) s += Wo[f*89+j] * (Wv[j*89+80+t] + bv[j]);
        ws[OFF_C2 + combo*720 + e6] = s;
    }
}

__global__ __launch_bounds__(256) void k_prep_cw(const float* __restrict__ W1,
                                                 const float* __restrict__ W2,
                                                 float* __restrict__ ws) {
    int l = blockIdx.y;
    int e = blockIdx.x * 256 + threadIdx.x;
    if (e >= 82 * 448) return;
    int k = e / 448, j = e % 448;
    int K = (l == 0) ? 82 : 80;
    float val = 0.f;
    if (k < K) {
        const float* Wr = ((l == 0) ? W1 : W2) + k * 80;
        if (j < 80) {
            val = Wr[j];
        } else if (j < 240) {
            int m = (j - 80) / 80, col = (j - 80) % 80;
            const float* G = ws + OFF_G + (l*2+m)*6400;
            float s = 0.f;
            for (int c = 0; c < 80; ++c) s += Wr[c] * G[c*80 + col];
            val = s;
        } else if (j < 276) {
            int q = j - 240; int m = q / 18; int qq = q % 18;
            int combo = l*2 + m;
            if (qq < 9) {
                const float* Ff = ws + OFF_FF + combo*720;
                float s = 0.f;
                for (int c = 0; c < 80; ++c) s += Wr[c] * Ff[c*9 + qq];
                val = s;
            } else {
                const float* Fg = ws + OFF_FG + combo*720;
                float s = 0.f;
                for (int c = 0; c < 80; ++c) s += Wr[c] * Fg[c*9 + qq - 9];
                val = s;
            }
        } else if (j >= 280 && j < 440) {
            int m = (j - 280) / 80, f = (j - 280) % 80;
            const float* M = ws + OFF_M + (l*2+m)*6400 + f*80;
            float s = 0.f;
            for (int c = 0; c < 80; ++c) s += Wr[c] * M[c];
            val = s;
        }
    }
    ws[OFF_CW + (size_t)l*82*448 + e] = val;
}

template<int K, bool TRANS>
__global__ __launch_bounds__(256) void k_gemm(const float* __restrict__ A,
                                              const float* __restrict__ CW,
                                              float* __restrict__ H,
                                              const float* __restrict__ ms) {
    __shared__ __align__(16) float AsT[K][72];
    __shared__ __align__(16) float Bs[K][68];
    int tid = threadIdx.x;
    int n0 = blockIdx.x * 64;
    int j0 = blockIdx.y * 64;
    float scale0 = 0.f;
    if constexpr (TRANS) scale0 = ms[80];
    for (int idx = tid; idx < 64 * K; idx += 256) {
        int r = idx / K, k = idx - r * K;
        float v = A[(size_t)(n0 + r) * K + k];
        if constexpr (TRANS) v = fmaxf(0.f, (v - ms[k]) * scale0);
        AsT[k][r] = v;
    }
    // B staging via float4 (CW rows 16B-aligned: base, 448-stride, j0 mult-64)
    for (int idx = tid; idx < K * 16; idx += 256) {
        int k = idx >> 4, c4 = idx & 15;
        *(float4*)(&Bs[k][c4 * 4]) = *(const float4*)(&CW[k * 448 + j0 + c4 * 4]);
    }
    __syncthreads();
    int r0 = (tid >> 4) * 4, c0 = (tid & 15) * 4;
    float acc[4][4] = {};
    #pragma unroll 2
    for (int k = 0; k < K; ++k) {
        float4 a4 = *(const float4*)(&AsT[k][r0]);
        float4 b4 = *(const float4*)(&Bs[k][c0]);
        acc[0][0] += a4.x*b4.x; acc[0][1] += a4.x*b4.y; acc[0][2] += a4.x*b4.z; acc[0][3] += a4.x*b4.w;
        acc[1][0] += a4.y*b4.x; acc[1][1] += a4.y*b4.y; acc[1][2] += a4.y*b4.z; acc[1][3] += a4.y*b4.w;
        acc[2][0] += a4.z*b4.x; acc[2][1] += a4.z*b4.y; acc[2][2] += a4.z*b4.z; acc[2][3] += a4.z*b4.w;
        acc[3][0] += a4.w*b4.x; acc[3][1] += a4.w*b4.y; acc[3][2] += a4.w*b4.z; acc[3][3] += a4.w*b4.w;
    }
    for (int i = 0; i < 4; ++i) {
        float4 v = make_float4(acc[i][0], acc[i][1], acc[i][2], acc[i][3]);
        *(float4*)(&H[(size_t)(n0 + r0 + i) * HWID + j0 + c0]) = v;
    }
}

// ---------------- fused attention v8: v3b verbatim + BATCHED stage only ----------------
// Diagnosis across v3b..v7: per-node wall ~25k cycles vs ~1.4k VALU — the stage loop's
// load->ds_write per iteration forces a vmcnt wait PER ITERATION (9 serial ~600cy+ round
// trips under queueing). v6 proved batching loads works mechanically but bundled 50+ extra
// live prefetch values -> compiler chose 60 VGPR and re-split. v8 = v3b with ONLY the stage
// batched: 9 loads -> named float4 regs -> one vmcnt drain -> 9 ds_writes. +36 VGPR peak,
// nothing else moved. __syncthreads retained (proven structure).
// Tripwire: VGPR <= 80 with dur ~190 => compiler split the batch again.
__global__ __launch_bounds__(128) void k_attn(const float* __restrict__ ws,
                                              const float* __restrict__ Hbuf,
                                              const int* __restrict__ nbr,
                                              const float* __restrict__ outb,
                                              const float* __restrict__ bvec,
                                              float* __restrict__ u,
                                              int l) {
    __shared__ __align__(16) float sS[2][9][242];  // h | hG1 | hG2 (cols 0:240), wave-private
    __shared__ float sP[2][2][9][9];
    __shared__ float sCC[2][81];
    int tid = threadIdx.x;
    int wave = tid >> 6, lane = tid & 63;
    int n = blockIdx.x * 2 + wave;
    int nv = nbr[n * 9 + (lane < 9 ? lane : 8)];
    int rr[9];
    #pragma unroll
    for (int s = 0; s < 9; ++s) rr[s] = __shfl(nv, s);

    // pair-1 (pp = lane < 81 always) f/g register prefetch
    int s1 = lane / 9, t1 = lane - s1 * 9;
    const float* rowS1 = Hbuf + (size_t)rr[s1] * HWID;
    const float* rowT1 = Hbuf + (size_t)rr[t1] * HWID;
    float f1a = rowS1[240 + t1], g1a = rowT1[249 + s1];
    float f2a = rowS1[258 + t1], g2a = rowT1[267 + s1];
    // pair-2 (pp2 = lane+64, valid for lane < 17)
    int pp2 = (lane < 17) ? (lane + 64) : 80;
    int s2 = pp2 / 9, t2 = pp2 - s2 * 9;
    const float* rowS2 = Hbuf + (size_t)rr[s2] * HWID;
    const float* rowT2 = Hbuf + (size_t)rr[t2] * HWID;
    float f1b = rowS2[240 + t2], g1b = rowT2[249 + s2];
    float f2b = rowS2[258 + t2], g2b = rowT2[267 + s2];

    // cc -> LDS (block-shared)
    for (int i = tid; i < 162; i += 128) sCC[0][i] = ws[OFF_CC + (l*2)*81 + i];

    // ---- stage 9 rows x 240 floats: BATCHED — 9 loads, one drain, 9 ds_writes ----
    float4 st0, st1, st2, st3, st4, st5, st6, st7, st8;
    {
        #define LD_ST(J, DST)                                                   \
        {   int i = lane + 64 * (J);                                            \
            int row = i / 60, c4 = i - row * 60;                                \
            int r = __shfl(nv, row);                                            \
            if (i < 540) DST = *(const float4*)(Hbuf + (size_t)r * HWID + c4 * 4); \
            else DST = make_float4(0.f,0.f,0.f,0.f); }
        LD_ST(0, st0) LD_ST(1, st1) LD_ST(2, st2) LD_ST(3, st3) LD_ST(4, st4)
        LD_ST(5, st5) LD_ST(6, st6) LD_ST(7, st7) LD_ST(8, st8)
        #undef LD_ST
    }
    {
        #define ST_ST(J, SRC)                                                   \
        {   int i = lane + 64 * (J);                                            \
            if (i < 540) {                                                      \
                int row = i / 60, c4 = i - row * 60;                            \
                *(float4*)(&sS[wave][row][c4 * 4]) = SRC; } }
        ST_ST(0, st0) ST_ST(1, st1) ST_ST(2, st2) ST_ST(3, st3) ST_ST(4, st4)
        ST_ST(5, st5) ST_ST(6, st6) ST_ST(7, st7) ST_ST(8, st8)
        #undef ST_ST
    }
    __syncthreads();

    const float rsE = 1.0f / 9.433981132056603f;  // 1/sqrt(89)
    // phase A: pair 1
    {
        float a0 = 0.f, a1 = 0.f, b0 = 0.f, b1 = 0.f;
        #pragma unroll
        for (int i = 0; i < 20; ++i) {
            float4 hh = *(const float4*)(&sS[wave][t1][4*i]);
            float4 g1 = *(const float4*)(&sS[wave][s1][80 + 4*i]);
            float4 g2 = *(const float4*)(&sS[wave][s1][160 + 4*i]);
            a0 += g1.x*hh.x + g1.y*hh.y; a1 += g1.z*hh.z + g1.w*hh.w;
            b0 += g2.x*hh.x + g2.y*hh.y; b1 += g2.z*hh.z + g2.w*hh.w;
        }
        sP[wave][0][s1][t1] = (a0 + a1 + f1a + g1a + sCC[0][lane]) * rsE;
        sP[wave][1][s1][t1] = (b0 + b1 + f2a + g2a + sCC[1][lane]) * rsE;
    }
    // phase A: pair 2 (17 lanes)
    if (lane < 17) {
        float a0 = 0.f, a1 = 0.f, b0 = 0.f, b1 = 0.f;
        #pragma unroll
        for (int i = 0; i < 20; ++i) {
            float4 hh = *(const float4*)(&sS[wave][t2][4*i]);
            float4 g1 = *(const float4*)(&sS[wave][s2][80 + 4*i]);
            float4 g2 = *(const float4*)(&sS[wave][s2][160 + 4*i]);
            a0 += g1.x*hh.x + g1.y*hh.y; a1 += g1.z*hh.z + g1.w*hh.w;
            b0 += g2.x*hh.x + g2.y*hh.y; b1 += g2.z*hh.z + g2.w*hh.w;
        }
        sP[wave][0][s2][t2] = (a0 + a1 + f1b + g1b + sCC[0][pp2]) * rsE;
        sP[wave][1][s2][t2] = (b0 + b1 + f2b + g2b + sCC[1][pp2]) * rsE;
    }
    __syncthreads();
    // phase B: softmax over t (18 rows per node)
    if (lane < 18) {
        int m = lane / 9, s = lane - m*9;
        float row[9]; float mx = -1e30f;
        #pragma unroll
        for (int t = 0; t < 9; ++t) { row[t] = sP[wave][m][s][t]; mx = fmaxf(mx, row[t]); }
        float sm = 0.f;
        #pragma unroll
        for (int t = 0; t < 9; ++t) { row[t] = __expf(row[t] - mx); sm += row[t]; }
        float inv = 1.f / sm;
        #pragma unroll
        for (int t = 0; t < 9; ++t) sP[wave][m][s][t] = row[t] * inv;
    }
    __syncthreads();
    // phase C: PV (v from global, coalesced in f) + base(LDS) + max + bias
    for (int f = lane; f < 80; f += 64) {
        float acc[9] = {};
        #pragma unroll
        for (int m = 0; m < 2; ++m) {
            const float* c2 = ws + OFF_C2 + (l*2+m)*720;
            #pragma unroll
            for (int t = 0; t < 9; ++t) {
                float vv = Hbuf[(size_t)rr[t]*HWID + 280 + m*80 + f] + c2[t*80 + f];
                #pragma unroll
                for (int s = 0; s < 9; ++s) acc[s] += sP[wave][m][s][t] * vv;
            }
        }
        float mx = -1e30f;
        #pragma unroll
        for (int s = 0; s < 9; ++s) mx = fmaxf(mx, acc[s] + sS[wave][s][f]);
        float bias = outb[(l*2)*89 + f] + outb[(l*2+1)*89 + f] + bvec[f];
        u[(size_t)n*80 + f] = mx + bias;
    }
}

__global__ __launch_bounds__(256) void k_colreduce(const float* __restrict__ u, float* __restrict__ stats) {
    __shared__ float ps[3][80], ps2[3][80];
    int tid = threadIdx.x;
    int c = tid % 80, rg = tid / 80;
    if (rg < 3) {
        float s = 0.f, s2 = 0.f;
        int rbase = blockIdx.x * 48 + rg * 16;
        for (int i = 0; i < 16; ++i) {
            int rw = rbase + i;
            if (rw < NN) {
                float v = u[(size_t)rw*80 + c];
                s += v; s2 += v*v;
            }
        }
        ps[rg][c] = s; ps2[rg][c] = s2;
    }
    __syncthreads();
    if (tid < 80) {
        atomicAdd(&stats[tid],      ps[0][tid] + ps[1][tid] + ps[2][tid]);
        atomicAdd(&stats[80 + tid], ps2[0][tid] + ps2[1][tid] + ps2[2][tid]);
    }
}

__global__ __launch_bounds__(128) void k_normscale(const float* __restrict__ stats, float* __restrict__ ms) {
    __shared__ float red[80];
    int t = threadIdx.x;
    if (t < 80) {
        float mean = stats[t] * (1.0f / (float)NN);
        ms[t] = mean;
        red[t] = stats[80 + t] - (float)NN * mean * mean;
    }
    __syncthreads();
    if (t == 0) {
        float ss = 0.f;
        for (int i = 0; i < 80; ++i) ss += red[i];
        ms[80] = 1.0f / sqrtf(1e-5f + ss * (1.0f / (float)NN));
    }
}

__global__ __launch_bounds__(256) void k_final(const float* __restrict__ x,
                                               const float* __restrict__ u2,
                                               const float* __restrict__ ms,
                                               float* __restrict__ out) {
    int g = blockIdx.x * 256 + threadIdx.x;
    int n = g / 80, f = g % 80;
    float scale0 = ms[80];
    float v = fmaxf(0.f, (u2[g] - ms[f]) * scale0);
    float o = x[(size_t)n*82 + f] + v;
    if (f == 79 && (o > 1.0f || o < -1.0f)) o = 0.f;
    out[g] = o * 0.5f;
}

extern "C" void kernel_launch(void* const* d_in, const int* in_sizes, int n_in,
                              void* d_out, int out_size, void* d_ws, size_t ws_size,
                              hipStream_t stream) {
    const float* x    = (const float*)d_in[0];
    const float* W1   = (const float*)d_in[1];
    const float* b1   = (const float*)d_in[2];
    const float* W2   = (const float*)d_in[3];
    const float* b2   = (const float*)d_in[4];
    const float* qkvw = (const float*)d_in[5];
    const float* qkvb = (const float*)d_in[6];
    const float* outw = (const float*)d_in[7];
    const float* outb = (const float*)d_in[8];
    const int*   nbr  = (const int*)d_in[9];
    float* ws = (float*)d_ws;
    float* out = (float*)d_out;

    float* H = ws + OFF_H;
    float* u = ws + OFF_U;

    hipMemsetAsync(ws + OFF_STATS, 0, 320 * sizeof(float), stream);
    k_prep_small<<<dim3(59, 4), 256, 0, stream>>>(qkvw, qkvb, outw, ws);
    k_prep_cw<<<dim3(144, 2), 256, 0, stream>>>(W1, W2, ws);

    k_gemm<82, false><<<dim3(512, 7), 256, 0, stream>>>(x, ws + OFF_CW, H, nullptr);
    k_attn<<<16384, 128, 0, stream>>>(ws, H, nbr, outb, b1, u, 0);
    k_colreduce<<<683, 256, 0, stream>>>(u, ws + OFF_STATS);
    k_normscale<<<1, 128, 0, stream>>>(ws + OFF_STATS, ws + OFF_MS);

    k_gemm<80, true><<<dim3(512, 7), 256, 0, stream>>>(u, ws + OFF_CW + 82*448, H, ws + OFF_MS);
    k_attn<<<16384, 128, 0, stream>>>(ws, H, nbr, outb, b2, u, 1);
    k_colreduce<<<683, 256, 0, stream>>>(u, ws + OFF_STATS + 160);
    k_normscale<<<1, 128, 0, stream>>>(ws + OFF_STATS + 160, ws + OFF_MS + 96);

    k_final<<<10240, 256, 0, stream>>>(x, u, ws + OFF_MS + 96, out);
}

// Round 7
// 501.426 us; speedup vs baseline: 2.7799x; 1.0433x over previous
//
#include <hip/hip_runtime.h>

#define NN 32768
#define HWID 448
// H cols: 0:80 h | 80:160 hG1 | 160:240 hG2 | 240:249 f1 | 249:258 g1 | 258:267 f2 | 267:276 g2 |
//         276:280 pad | 280:360 hvo1 | 360:440 hvo2 | 440:448 pad

// ---- workspace float offsets ----
#define OFF_G     0
#define OFF_M     25600
#define OFF_FF    51200
#define OFF_FG    54080
#define OFF_CC    56960
#define OFF_C2    57284
#define OFF_CW    60164
#define OFF_STATS 133636
#define OFF_MS    133956
#define OFF_H     134148
#define OFF_U     14814212

__global__ __launch_bounds__(256) void k_prep_small(const float* __restrict__ qkvw,
                                                    const float* __restrict__ qkvb,
                                                    const float* __restrict__ outw,
                                                    float* __restrict__ ws) {
    int combo = blockIdx.y;
    int e = blockIdx.x * 256 + threadIdx.x;
    const float* Wq = qkvw + combo * 267 * 89;
    const float* Wk = Wq + 89 * 89;
    const float* Wv = Wq + 178 * 89;
    const float* bq = qkvb + combo * 267;
    const float* bk = bq + 89;
    const float* bv = bq + 178;
    const float* Wo = outw + combo * 89 * 89;
    if (e < 6400) {
        int a = e / 80, b = e % 80;
        float s = 0.f;
        for (int j = 0; j < 89; ++j) s += Wq[j*89+a] * Wk[j*89+b];
        ws[OFF_G + combo*6400 + e] = s;
    } else if (e < 12800) {
        int e2 = e - 6400; int f = e2 / 80, c = e2 % 80;
        float s = 0.f;
        for (int j = 0; j < 89; ++j) s += Wo[f*89+j] * Wv[j*89+c];
        ws[OFF_M + combo*6400 + e2] = s;
    } else if (e < 13520) {
        int e3 = e - 12800; int a = e3 / 9, t = e3 % 9;
        float s = 0.f;
        for (int j = 0; j < 89; ++j) s += Wq[j*89+a] * (Wk[j*89+80+t] + bk[j]);
        ws[OFF_FF + combo*720 + e3] = s;
    } else if (e < 14240) {
        int e4 = e - 13520; int a = e4 / 9, si = e4 % 9;
        float s = 0.f;
        for (int j = 0; j < 89; ++j) s += Wk[j*89+a] * (Wq[j*89+80+si] + bq[j]);
        ws[OFF_FG + combo*720 + e4] = s;
    } else if (e < 14321) {
        int e5 = e - 14240; int si = e5 / 9, t = e5 % 9;
        float s = 0.f;
        for (int j = 0; j < 89; ++j) s += (Wq[j*89+80+si] + bq[j]) * (Wk[j*89+80+t] + bk[j]);
        ws[OFF_CC + combo*81 + e5] = s;
    } else if (e < 15041) {
        int e6 = e - 14321; int t = e6 / 80, f = e6 % 80;
        float s = 0.f;
        for (int j = 0; j < 89; ++j) s += Wo[f*89+j] * (Wv[j*89+80+t] + bv[j]);
        ws[OFF_C2 + combo*720 + e6] = s;
    }
}

__global__ __launch_bounds__(256) void k_prep_cw(const float* __restrict__ W1,
                                                 const float* __restrict__ W2,
                                                 float* __restrict__ ws) {
    int l = blockIdx.y;
    int e = blockIdx.x * 256 + threadIdx.x;
    if (e >= 82 * 448) return;
    int k = e / 448, j = e % 448;
    int K = (l == 0) ? 82 : 80;
    float val = 0.f;
    if (k < K) {
        const float* Wr = ((l == 0) ? W1 : W2) + k * 80;
        if (j < 80) {
            val = Wr[j];
        } else if (j < 240) {
            int m = (j - 80) / 80, col = (j - 80) % 80;
            const float* G = ws + OFF_G + (l*2+m)*6400;
            float s = 0.f;
            for (int c = 0; c < 80; ++c) s += Wr[c] * G[c*80 + col];
            val = s;
        } else if (j < 276) {
            int q = j - 240; int m = q / 18; int qq = q % 18;
            int combo = l*2 + m;
            if (qq < 9) {
                const float* Ff = ws + OFF_FF + combo*720;
                float s = 0.f;
                for (int c = 0; c < 80; ++c) s += Wr[c] * Ff[c*9 + qq];
                val = s;
            } else {
                const float* Fg = ws + OFF_FG + combo*720;
                float s = 0.f;
                for (int c = 0; c < 80; ++c) s += Wr[c] * Fg[c*9 + qq - 9];
                val = s;
            }
        } else if (j >= 280 && j < 440) {
            int m = (j - 280) / 80, f = (j - 280) % 80;
            const float* M = ws + OFF_M + (l*2+m)*6400 + f*80;
            float s = 0.f;
            for (int c = 0; c < 80; ++c) s += Wr[c] * M[c];
            val = s;
        }
    }
    ws[OFF_CW + (size_t)l*82*448 + e] = val;
}

template<int K, bool TRANS>
__global__ __launch_bounds__(256) void k_gemm(const float* __restrict__ A,
                                              const float* __restrict__ CW,
                                              float* __restrict__ H,
                                              const float* __restrict__ ms) {
    __shared__ __align__(16) float AsT[K][72];
    __shared__ __align__(16) float Bs[K][68];
    int tid = threadIdx.x;
    int n0 = blockIdx.x * 64;
    int j0 = blockIdx.y * 64;
    float scale0 = 0.f;
    if constexpr (TRANS) scale0 = ms[80];
    for (int idx = tid; idx < 64 * K; idx += 256) {
        int r = idx / K, k = idx - r * K;
        float v = A[(size_t)(n0 + r) * K + k];
        if constexpr (TRANS) v = fmaxf(0.f, (v - ms[k]) * scale0);
        AsT[k][r] = v;
    }
    // B staging via float4 (CW rows 16B-aligned: base, 448-stride, j0 mult-64)
    for (int idx = tid; idx < K * 16; idx += 256) {
        int k = idx >> 4, c4 = idx & 15;
        *(float4*)(&Bs[k][c4 * 4]) = *(const float4*)(&CW[k * 448 + j0 + c4 * 4]);
    }
    __syncthreads();
    int r0 = (tid >> 4) * 4, c0 = (tid & 15) * 4;
    float acc[4][4] = {};
    #pragma unroll 2
    for (int k = 0; k < K; ++k) {
        float4 a4 = *(const float4*)(&AsT[k][r0]);
        float4 b4 = *(const float4*)(&Bs[k][c0]);
        acc[0][0] += a4.x*b4.x; acc[0][1] += a4.x*b4.y; acc[0][2] += a4.x*b4.z; acc[0][3] += a4.x*b4.w;
        acc[1][0] += a4.y*b4.x; acc[1][1] += a4.y*b4.y; acc[1][2] += a4.y*b4.z; acc[1][3] += a4.y*b4.w;
        acc[2][0] += a4.z*b4.x; acc[2][1] += a4.z*b4.y; acc[2][2] += a4.z*b4.z; acc[2][3] += a4.z*b4.w;
        acc[3][0] += a4.w*b4.x; acc[3][1] += a4.w*b4.y; acc[3][2] += a4.w*b4.z; acc[3][3] += a4.w*b4.w;
    }
    for (int i = 0; i < 4; ++i) {
        float4 v = make_float4(acc[i][0], acc[i][1], acc[i][2], acc[i][3]);
        *(float4*)(&H[(size_t)(n0 + r0 + i) * HWID + j0 + c0]) = v;
    }
}

// ---------------- fused attention v9: v8 + phase-C V/c2 prefetched into the single burst ------
// (Resubmission — R6 bench was an infra failure, kernel never ran.)
// v8 (batched stage, one vmcnt drain) proved the mechanism: 191->144 us, VGPR 128, pred matched.
// Remaining serial latency exposures: (0) nbr load, (1) stage burst, (2) phase-C's 36 V + 18 c2
// gathers issued AFTER the softmax barrier (fully exposed tail). v9 moves (2) into the pre-
// barrier burst: issued right after the stage ds_writes (stage regs die there), c2 folded in at
// prefetch time (bit-identical to v8's vv = Hbuf[..] + c2[..]). The THREE __syncthreads are the
// load-sinking fences that made v8's batch survive (v6's wsync-only variant re-split at 60 VGPR).
// Tripwire: VGPR <= 100 => scheduler re-split => revert & pivot to GEMM.
__global__ __launch_bounds__(128) void k_attn(const float* __restrict__ ws,
                                              const float* __restrict__ Hbuf,
                                              const int* __restrict__ nbr,
                                              const float* __restrict__ outb,
                                              const float* __restrict__ bvec,
                                              float* __restrict__ u,
                                              int l) {
    __shared__ __align__(16) float sS[2][9][242];  // h | hG1 | hG2 (cols 0:240), wave-private
    __shared__ float sP[2][2][9][9];
    __shared__ float sCC[2][81];
    int tid = threadIdx.x;
    int wave = tid >> 6, lane = tid & 63;
    int n = blockIdx.x * 2 + wave;
    int nv = nbr[n * 9 + (lane < 9 ? lane : 8)];
    int rr[9];
    #pragma unroll
    for (int s = 0; s < 9; ++s) rr[s] = __shfl(nv, s);

    // pair-1 (pp = lane < 81 always) f/g register prefetch
    int s1 = lane / 9, t1 = lane - s1 * 9;
    const float* rowS1 = Hbuf + (size_t)rr[s1] * HWID;
    const float* rowT1 = Hbuf + (size_t)rr[t1] * HWID;
    float f1a = rowS1[240 + t1], g1a = rowT1[249 + s1];
    float f2a = rowS1[258 + t1], g2a = rowT1[267 + s1];
    // pair-2 (pp2 = lane+64, valid for lane < 17)
    int pp2 = (lane < 17) ? (lane + 64) : 80;
    int s2 = pp2 / 9, t2 = pp2 - s2 * 9;
    const float* rowS2 = Hbuf + (size_t)rr[s2] * HWID;
    const float* rowT2 = Hbuf + (size_t)rr[t2] * HWID;
    float f1b = rowS2[240 + t2], g1b = rowT2[249 + s2];
    float f2b = rowS2[258 + t2], g2b = rowT2[267 + s2];

    // cc -> LDS (block-shared)
    for (int i = tid; i < 162; i += 128) sCC[0][i] = ws[OFF_CC + (l*2)*81 + i];

    // ---- stage 9 rows x 240 floats: BATCHED — 9 loads, one drain, 9 ds_writes ----
    float4 st0, st1, st2, st3, st4, st5, st6, st7, st8;
    {
        #define LD_ST(J, DST)                                                   \
        {   int i = lane + 64 * (J);                                            \
            int row = i / 60, c4 = i - row * 60;                                \
            int r = __shfl(nv, row);                                            \
            if (i < 540) DST = *(const float4*)(Hbuf + (size_t)r * HWID + c4 * 4); \
            else DST = make_float4(0.f,0.f,0.f,0.f); }
        LD_ST(0, st0) LD_ST(1, st1) LD_ST(2, st2) LD_ST(3, st3) LD_ST(4, st4)
        LD_ST(5, st5) LD_ST(6, st6) LD_ST(7, st7) LD_ST(8, st8)
        #undef LD_ST
    }
    {
        #define ST_ST(J, SRC)                                                   \
        {   int i = lane + 64 * (J);                                            \
            if (i < 540) {                                                      \
                int row = i / 60, c4 = i - row * 60;                            \
                *(float4*)(&sS[wave][row][c4 * 4]) = SRC; } }
        ST_ST(0, st0) ST_ST(1, st1) ST_ST(2, st2) ST_ST(3, st3) ST_ST(4, st4)
        ST_ST(5, st5) ST_ST(6, st6) ST_ST(7, st7) ST_ST(8, st8)
        #undef ST_ST
    }

    // ---- phase-C V prefetch (+ c2 folded, identical arithmetic to inline version) ----
    // Issued before barrier-1: its drain merges this latency into the stage exposure.
    const float* c2a = ws + OFF_C2 + (l*2)*720;
    const float* c2b = c2a + 720;
    int fB = (lane < 16) ? (lane + 64) : 79;
    float va0[9], va1[9], vb0[9], vb1[9];
    #pragma unroll
    for (int t = 0; t < 9; ++t) {
        const float* rowp = Hbuf + (size_t)rr[t] * HWID + 280;
        va0[t] = rowp[lane]      + c2a[t*80 + lane];
        va1[t] = rowp[80 + lane] + c2b[t*80 + lane];
        vb0[t] = rowp[fB]        + c2a[t*80 + fB];
        vb1[t] = rowp[80 + fB]   + c2b[t*80 + fB];
    }
    // bias scalars (L2-hot), also pre-barrier
    float biasA = outb[(l*2)*89 + lane] + outb[(l*2+1)*89 + lane] + bvec[lane < 80 ? lane : 0];
    float biasB = (lane < 16) ? (outb[(l*2)*89 + fB] + outb[(l*2+1)*89 + fB] + bvec[fB]) : 0.f;

    __syncthreads();

    const float rsE = 1.0f / 9.433981132056603f;  // 1/sqrt(89)
    // phase A: pair 1
    {
        float a0 = 0.f, a1 = 0.f, b0 = 0.f, b1 = 0.f;
        #pragma unroll
        for (int i = 0; i < 20; ++i) {
            float4 hh = *(const float4*)(&sS[wave][t1][4*i]);
            float4 g1 = *(const float4*)(&sS[wave][s1][80 + 4*i]);
            float4 g2 = *(const float4*)(&sS[wave][s1][160 + 4*i]);
            a0 += g1.x*hh.x + g1.y*hh.y; a1 += g1.z*hh.z + g1.w*hh.w;
            b0 += g2.x*hh.x + g2.y*hh.y; b1 += g2.z*hh.z + g2.w*hh.w;
        }
        sP[wave][0][s1][t1] = (a0 + a1 + f1a + g1a + sCC[0][lane]) * rsE;
        sP[wave][1][s1][t1] = (b0 + b1 + f2a + g2a + sCC[1][lane]) * rsE;
    }
    // phase A: pair 2 (17 lanes)
    if (lane < 17) {
        float a0 = 0.f, a1 = 0.f, b0 = 0.f, b1 = 0.f;
        #pragma unroll
        for (int i = 0; i < 20; ++i) {
            float4 hh = *(const float4*)(&sS[wave][t2][4*i]);
            float4 g1 = *(const float4*)(&sS[wave][s2][80 + 4*i]);
            float4 g2 = *(const float4*)(&sS[wave][s2][160 + 4*i]);
            a0 += g1.x*hh.x + g1.y*hh.y; a1 += g1.z*hh.z + g1.w*hh.w;
            b0 += g2.x*hh.x + g2.y*hh.y; b1 += g2.z*hh.z + g2.w*hh.w;
        }
        sP[wave][0][s2][t2] = (a0 + a1 + f1b + g1b + sCC[0][pp2]) * rsE;
        sP[wave][1][s2][t2] = (b0 + b1 + f2b + g2b + sCC[1][pp2]) * rsE;
    }
    __syncthreads();
    // phase B: softmax over t (18 rows per node)
    if (lane < 18) {
        int m = lane / 9, s = lane - m*9;
        float row[9]; float mx = -1e30f;
        #pragma unroll
        for (int t = 0; t < 9; ++t) { row[t] = sP[wave][m][s][t]; mx = fmaxf(mx, row[t]); }
        float sm = 0.f;
        #pragma unroll
        for (int t = 0; t < 9; ++t) { row[t] = __expf(row[t] - mx); sm += row[t]; }
        float inv = 1.f / sm;
        #pragma unroll
        for (int t = 0; t < 9; ++t) sP[wave][m][s][t] = row[t] * inv;
    }
    __syncthreads();
    // phase C: PV on prefetched regs (c2 already folded) + base(LDS) + max + bias
    {
        float acc[9] = {};
        #pragma unroll
        for (int t = 0; t < 9; ++t) {
            float v0 = va0[t], v1 = va1[t];
            #pragma unroll
            for (int s = 0; s < 9; ++s) acc[s] += sP[wave][0][s][t] * v0 + sP[wave][1][s][t] * v1;
        }
        float mx = -1e30f;
        #pragma unroll
        for (int s = 0; s < 9; ++s) mx = fmaxf(mx, acc[s] + sS[wave][s][lane]);
        u[(size_t)n*80 + lane] = mx + biasA;
    }
    if (lane < 16) {
        float acc[9] = {};
        #pragma unroll
        for (int t = 0; t < 9; ++t) {
            float v0 = vb0[t], v1 = vb1[t];
            #pragma unroll
            for (int s = 0; s < 9; ++s) acc[s] += sP[wave][0][s][t] * v0 + sP[wave][1][s][t] * v1;
        }
        float mx = -1e30f;
        #pragma unroll
        for (int s = 0; s < 9; ++s) mx = fmaxf(mx, acc[s] + sS[wave][s][fB]);
        u[(size_t)n*80 + fB] = mx + biasB;
    }
}

__global__ __launch_bounds__(256) void k_colreduce(const float* __restrict__ u, float* __restrict__ stats) {
    __shared__ float ps[3][80], ps2[3][80];
    int tid = threadIdx.x;
    int c = tid % 80, rg = tid / 80;
    if (rg < 3) {
        float s = 0.f, s2 = 0.f;
        int rbase = blockIdx.x * 48 + rg * 16;
        for (int i = 0; i < 16; ++i) {
            int rw = rbase + i;
            if (rw < NN) {
                float v = u[(size_t)rw*80 + c];
                s += v; s2 += v*v;
            }
        }
        ps[rg][c] = s; ps2[rg][c] = s2;
    }
    __syncthreads();
    if (tid < 80) {
        atomicAdd(&stats[tid],      ps[0][tid] + ps[1][tid] + ps[2][tid]);
        atomicAdd(&stats[80 + tid], ps2[0][tid] + ps2[1][tid] + ps2[2][tid]);
    }
}

__global__ __launch_bounds__(128) void k_normscale(const float* __restrict__ stats, float* __restrict__ ms) {
    __shared__ float red[80];
    int t = threadIdx.x;
    if (t < 80) {
        float mean = stats[t] * (1.0f / (float)NN);
        ms[t] = mean;
        red[t] = stats[80 + t] - (float)NN * mean * mean;
    }
    __syncthreads();
    if (t == 0) {
        float ss = 0.f;
        for (int i = 0; i < 80; ++i) ss += red[i];
        ms[80] = 1.0f / sqrtf(1e-5f + ss * (1.0f / (float)NN));
    }
}

__global__ __launch_bounds__(256) void k_final(const float* __restrict__ x,
                                               const float* __restrict__ u2,
                                               const float* __restrict__ ms,
                                               float* __restrict__ out) {
    int g = blockIdx.x * 256 + threadIdx.x;
    int n = g / 80, f = g % 80;
    float scale0 = ms[80];
    float v = fmaxf(0.f, (u2[g] - ms[f]) * scale0);
    float o = x[(size_t)n*82 + f] + v;
    if (f == 79 && (o > 1.0f || o < -1.0f)) o = 0.f;
    out[g] = o * 0.5f;
}

extern "C" void kernel_launch(void* const* d_in, const int* in_sizes, int n_in,
                              void* d_out, int out_size, void* d_ws, size_t ws_size,
                              hipStream_t stream) {
    const float* x    = (const float*)d_in[0];
    const float* W1   = (const float*)d_in[1];
    const float* b1   = (const float*)d_in[2];
    const float* W2   = (const float*)d_in[3];
    const float* b2   = (const float*)d_in[4];
    const float* qkvw = (const float*)d_in[5];
    const float* qkvb = (const float*)d_in[6];
    const float* outw = (const float*)d_in[7];
    const float* outb = (const float*)d_in[8];
    const int*   nbr  = (const int*)d_in[9];
    float* ws = (float*)d_ws;
    float* out = (float*)d_out;

    float* H = ws + OFF_H;
    float* u = ws + OFF_U;

    hipMemsetAsync(ws + OFF_STATS, 0, 320 * sizeof(float), stream);
    k_prep_small<<<dim3(59, 4), 256, 0, stream>>>(qkvw, qkvb, outw, ws);
    k_prep_cw<<<dim3(144, 2), 256, 0, stream>>>(W1, W2, ws);

    k_gemm<82, false><<<dim3(512, 7), 256, 0, stream>>>(x, ws + OFF_CW, H, nullptr);
    k_attn<<<16384, 128, 0, stream>>>(ws, H, nbr, outb, b1, u, 0);
    k_colreduce<<<683, 256, 0, stream>>>(u, ws + OFF_STATS);
    k_normscale<<<1, 128, 0, stream>>>(ws + OFF_STATS, ws + OFF_MS);

    k_gemm<80, true><<<dim3(512, 7), 256, 0, stream>>>(u, ws + OFF_CW + 82*448, H, ws + OFF_MS);
    k_attn<<<16384, 128, 0, stream>>>(ws, H, nbr, outb, b2, u, 1);
    k_colreduce<<<683, 256, 0, stream>>>(u, ws + OFF_STATS + 160);
    k_normscale<<<1, 128, 0, stream>>>(ws + OFF_STATS + 160, ws + OFF_MS + 96);

    k_final<<<10240, 256, 0, stream>>>(x, u, ws + OFF_MS + 96, out);
}